// Round 6
// baseline (326.362 us; speedup 1.0000x reference)
//
#include <hip/hip_runtime.h>
#include <hip/hip_bf16.h>

#define N_NODES 50000
#define E_EDGES 800000
#define EP_EDGES 850000   // E + N self loops
#define IN_DIM 160
#define HEADS 4
#define HID 64
#define C1 256            // HEADS*HID
#define NEG_SLOPE 0.2f
#define BN_EPS 1e-5f

typedef __attribute__((ext_vector_type(8))) short bf16x8;
typedef __attribute__((ext_vector_type(4))) float f32x4;
typedef _Float16 h2 __attribute__((ext_vector_type(2)));

__device__ __forceinline__ float b2f(ushort u) {
    return __uint_as_float(((unsigned)u) << 16);
}
__device__ __forceinline__ ushort f2b(float f) {
    __hip_bfloat16 h = __float2bfloat16(f);
    return *reinterpret_cast<ushort*>(&h);
}
__device__ __forceinline__ ushort f2h(float f) {
    union { _Float16 h; ushort u; } c;
    c.h = (_Float16)f;
    return c.u;
}
__device__ __forceinline__ float lo16(uint u) { return __uint_as_float(u << 16); }
__device__ __forceinline__ float hi16(uint u) { return __uint_as_float(u & 0xffff0000u); }
__device__ __forceinline__ h2 uh(uint u) {
    union { uint u; h2 h; } c; c.u = u; return c.h;
}

// ---- in-kernel dtype probes (wave-wide, 1 read + ballot) ----
__device__ __forceinline__ bool probe_f32(const ushort* xraw) {
    int lane = threadIdx.x & 63;
    float a = fabsf(b2f(xraw[2 * lane]));
    unsigned long long m = __ballot(a > 1e-6f && a < 1e6f);
    return __popcll(m) < 48;
}
__device__ __forceinline__ bool probe_i64(const int* eraw) {
    int lane = threadIdx.x & 63;
    unsigned long long m = __ballot(eraw[2 * lane + 1] != 0);
    return __popcll(m) < 8;
}

// DPP-based add of a permuted copy: pure VALU pipe
template<int CTRL>
__device__ __forceinline__ float dpp_add(float p) {
    int t = __builtin_amdgcn_update_dpp(0, __float_as_int(p), CTRL, 0xf, 0xf, true);
    return p + __int_as_float(t);
}
// sum over each 16-lane row; all 16 lanes get the row total
__device__ __forceinline__ float row16_sum(float p) {
    p = dpp_add<0xB1>(p);    // quad_perm xor1
    p = dpp_add<0x4E>(p);    // quad_perm xor2
    p = dpp_add<0x124>(p);   // row_ror:4
    p = dpp_add<0x128>(p);   // row_ror:8
    return p;
}

// ---------------- fused front-end: weight swizzle + params | A->bf16 cvt | hist(+epos) ----------------
// deg must be zeroed (hipMemsetAsync) before this kernel.
#define NB_SWZ 62
#define NB_CVT 3907   // 1,000,000 threads x 8 elems = 8,000,000 = 50000*160
#define NB_HIST 3321

struct SW2 {
    const void* W[5];    // raw Wl1, Wr1, Ws, Wl2, Wr2
    ushort* D[5];        // D[3],D[4] used for Wl2/Wr2; D[0..2] unused (U instead)
    ushort* U;           // unified frag buffer for Wl1|Wr1|Ws: [kb][f=0..35][lane][8]
    int NT[5];
    int base[5];
    const void* sp[19];  // raw small tensors
    const void* xraw;
};

__global__ void front_k(const int* __restrict__ ei, int* __restrict__ deg,
                        int* __restrict__ epos, SW2 s, ushort* __restrict__ params,
                        ushort* __restrict__ Abf) {
    const int b = blockIdx.x;
    if (b < NB_SWZ) {
        const bool f32 = probe_f32((const ushort*)s.xraw);
        if (b < 61) {
            int idx = b * 256 + threadIdx.x;     // < 15616
            int seg = 0;
            #pragma unroll
            for (int k = 1; k < 5; ++k) seg += (idx >= s.base[k]) ? 1 : 0;
            int li = idx - s.base[seg];
            int NT = s.NT[seg];
            int N = NT << 4;
            int lane = li & 63;
            int ft = li >> 6;
            int kb = ft / NT, t = ft - kb * NT;
            int q = lane >> 4, m = lane & 15;
            const float* pf = (const float*)s.W[seg];
            const ushort* pu = (const ushort*)s.W[seg];
            ushort* d;
            if (seg < 3) {
                const int FO = (seg == 0) ? 0 : (seg == 1) ? 16 : 32;
                d = s.U + ((size_t)(kb * 36 + FO + t) * 64 + lane) * 8;
            } else {
                d = s.D[seg] + (size_t)li * 8;
            }
            #pragma unroll
            for (int j = 0; j < 8; ++j) {
                size_t src = (size_t)(kb * 32 + q * 8 + j) * N + t * 16 + m;
                d[j] = f32 ? f2b(pf[src]) : pu[src];
            }
        } else {
            const int SZ[19] = {256,256,256,256,256,256,256,256,
                                64,64,64,64,64,64,64,64,64,64, 1};
            const int OF[19] = {40960,82176,82432,82688,82944,83200,83456,83712,
                                100352,116800,116864,116928,116992,117056,117120,117184,
                                127488,127552, 127616};
            for (int e = threadIdx.x; e < 2689; e += 256) {
                int rem = e, t = 0;
                while (rem >= SZ[t]) { rem -= SZ[t]; ++t; }
                const float* pf = (const float*)s.sp[t];
                const ushort* pu = (const ushort*)s.sp[t];
                float val = f32 ? pf[rem] : b2f(pu[rem]);
                // att1 (t==2) and att2 (t==10) stored as fp16 for packed-math convs
                params[OF[t] + rem] = (t == 2 || t == 10) ? f2h(val) : f2b(val);
            }
        }
    } else if (b < NB_SWZ + NB_CVT) {
        // ---- A -> contiguous bf16 [N][160] ----
        const bool f32 = probe_f32((const ushort*)s.xraw);
        int idx = (b - NB_SWZ) * 256 + threadIdx.x;    // 16B output chunk
        if (idx < 1000000) {
            if (f32) {
                const float* px = (const float*)s.xraw + (size_t)idx * 8;
                bf16x8 r;
                #pragma unroll
                for (int j = 0; j < 8; ++j) r[j] = (short)f2b(px[j]);
                *(bf16x8*)(Abf + (size_t)idx * 8) = r;
            } else {
                *(uint4*)(Abf + (size_t)idx * 8) =
                    *(const uint4*)((const ushort*)s.xraw + (size_t)idx * 8);
            }
        }
    } else {
        const bool i64 = probe_i64(ei);
        int e = (b - NB_SWZ - NB_CVT) * 256 + threadIdx.x;
        if (e >= EP_EDGES) return;
        int dst;
        if (e < E_EDGES) {
            int idx = E_EDGES + e;
            dst = i64 ? ei[2 * idx] : ei[idx];
        } else dst = e - E_EDGES;
        epos[e] = atomicAdd(&deg[dst], 1);   // slot within node; reused by scatter
    }
}

// ---------------- block scan via wave shfl + LDS (2 barriers) ----------------
__global__ __launch_bounds__(1024) void scan1_k(const int* __restrict__ deg,
                                                int* __restrict__ exc,
                                                int* __restrict__ bsum) {
    __shared__ int wsum[16];
    const int t = threadIdx.x;
    const int lane = t & 63, w = t >> 6;
    int i = blockIdx.x * 1024 + t;
    int v = (i < N_NODES) ? deg[i] : 0;
    int sIncl = v;
    #pragma unroll
    for (int d = 1; d < 64; d <<= 1) {
        int u = __shfl_up(sIncl, d);
        if (lane >= d) sIncl += u;
    }
    if (lane == 63) wsum[w] = sIncl;
    __syncthreads();
    if (w == 0) {
        int p = (lane < 16) ? wsum[lane] : 0;
        #pragma unroll
        for (int d = 1; d < 16; d <<= 1) {
            int u = __shfl_up(p, d);
            if (lane >= d) p += u;
        }
        if (lane < 16) wsum[lane] = p;
    }
    __syncthreads();
    int base = (w > 0) ? wsum[w - 1] : 0;
    int incl = base + sIncl;
    if (i < N_NODES) exc[i] = incl - v;
    if (t == 1023) bsum[blockIdx.x] = incl;
}

// 1-wave exclusive scan of the 49 chunk sums; also closes exc[N]
__global__ void scan2_k(const int* __restrict__ bsum, int* __restrict__ cp,
                        int* __restrict__ exc) {
    int lane = threadIdx.x;   // 64
    int v = (lane < 49) ? bsum[lane] : 0;
    int orig = v;
    #pragma unroll
    for (int d = 1; d < 64; d <<= 1) {
        int u = __shfl_up(v, d);
        if (lane >= d) v += u;
    }
    if (lane < 49) cp[lane] = v - orig;               // exclusive prefix
    if (lane == 48) exc[N_NODES] = EP_EDGES - (v - orig);
}

// ---------------- scatter (atomic-free), own kernel: no LDS -> full occupancy ----------------
__global__ __launch_bounds__(256) void scatter_k(const int* __restrict__ ei,
                                                 const int* __restrict__ epos,
                                                 const int* __restrict__ exc,
                                                 const int* __restrict__ cp,
                                                 int* __restrict__ col) {
    const bool i64 = probe_i64(ei);
    int e = blockIdx.x * 256 + threadIdx.x;
    if (e >= EP_EDGES) return;
    int src, dst;
    if (e < E_EDGES) {
        if (i64) { src = ei[2 * e]; dst = ei[2 * (E_EDGES + e)]; }
        else     { src = ei[e];     dst = ei[E_EDGES + e]; }
    } else { src = e - E_EDGES; dst = src; }
    col[exc[dst] + cp[dst >> 10] + epos[e]] = src;
}

// ---------------- gemm3: bf16-A, LDS-staged B slice, 2 row-tiles/wave ----------------
// grid = 391 row-blocks (128 rows) x 4 col-groups (9 frags = 144 cols)
// LDS: cg slice of U = 9 frags x 5 kb x 1KB = 46080 B -> 3 blocks/CU
#define NB_RB 391

__global__ __launch_bounds__(256, 3) void gemm3_k(const ushort* __restrict__ Abf,
                                                  const ushort* __restrict__ U,
                                                  const ushort* __restrict__ bi1,
                                                  const ushort* __restrict__ bi2,
                                                  const ushort* __restrict__ bi3,
                                                  ushort* __restrict__ o1,
                                                  ushort* __restrict__ o2,
                                                  ushort* __restrict__ o3,
                                                  int M) {
    __shared__ ushort Bs[23040];           // 45 frags x 64 lanes x 8 ushorts = 46080 B
    const int cg = blockIdx.x & 3;
    const int rb = blockIdx.x >> 2;
    const int tid = threadIdx.x;
    // ---- stage cg slice: 2880 x 16B chunks ----
    #pragma unroll
    for (int t = 0; t < 12; ++t) {
        int c = t * 256 + tid;
        if (c < 2880) {
            int lf = c >> 6;               // local frag 0..44
            int kb = lf / 9, jj = lf - kb * 9;
            int ln = c & 63;
            *(uint4*)(Bs + (size_t)c * 8) =
                *(const uint4*)(U + ((size_t)((kb * 36 + cg * 9 + jj) * 64 + ln)) * 8);
        }
    }
    __syncthreads();
    const int wave = tid >> 6, lane = tid & 63;
    const int row0 = rb * 128 + wave * 32;
    const bool ok0 = row0 < M, ok1 = row0 + 16 < M;   // tiles 16-aligned, M%16==0
    const int car0 = ok0 ? row0 + (lane & 15) : 0;
    const int car1 = ok1 ? row0 + 16 + (lane & 15) : 0;
    const int aoff = (lane >> 4) * 8;
    f32x4 a0[9] = {}, a1[9] = {};
    #pragma unroll
    for (int kb = 0; kb < 5; ++kb) {
        bf16x8 af0 = *(const bf16x8*)(Abf + (size_t)car0 * IN_DIM + aoff + kb * 32);
        bf16x8 af1 = *(const bf16x8*)(Abf + (size_t)car1 * IN_DIM + aoff + kb * 32);
        #pragma unroll
        for (int jj = 0; jj < 9; ++jj) {
            bf16x8 bfr = *(const bf16x8*)(Bs + (size_t)((kb * 9 + jj) * 64 + lane) * 8);
            a0[jj] = __builtin_amdgcn_mfma_f32_16x16x32_bf16(af0, bfr, a0[jj], 0, 0, 0);
            a1[jj] = __builtin_amdgcn_mfma_f32_16x16x32_bf16(af1, bfr, a1[jj], 0, 0, 0);
        }
    }
    const int cn = lane & 15, cq = lane >> 4;
    #pragma unroll
    for (int rt = 0; rt < 2; ++rt) {
        const bool ok = rt ? ok1 : ok0;
        if (!ok) continue;
        const int rbase = row0 + rt * 16;
        #pragma unroll
        for (int jj = 0; jj < 9; ++jj) {
            const int f = cg * 9 + jj;
            ushort* op; int ldc, colb; const ushort* bp_; bool tobf;
            if (f < 16)      { op = o1; ldc = C1;  colb = f * 16;        bp_ = bi1 + f * 16;        tobf = false; }
            else if (f < 32) { op = o2; ldc = C1;  colb = (f - 16) * 16; bp_ = bi2 + (f - 16) * 16; tobf = false; }
            else             { op = o3; ldc = HID; colb = (f - 32) * 16; bp_ = bi3 + (f - 32) * 16; tobf = true;  }
            const float bb = b2f(bp_[cn]);
            const f32x4 av = rt ? a1[jj] : a0[jj];
            #pragma unroll
            for (int r = 0; r < 4; ++r) {
                const int grow = rbase + cq * 4 + r;
                const float v = av[r] + bb;
                op[(size_t)grow * ldc + colb + cn] = tobf ? f2b(v) : f2h(v);
            }
        }
    }
}

// ---------------- fused layer-2 MFMA GEMM: xl2(64) + xr2(64), K=256 ----------------
__global__ __launch_bounds__(256) void gemm2_k(const ushort* __restrict__ A,
                                               const ushort* __restrict__ B1,
                                               const ushort* __restrict__ B2,
                                               const ushort* __restrict__ bi1,
                                               const ushort* __restrict__ bi2,
                                               ushort* __restrict__ o1,
                                               ushort* __restrict__ o2,
                                               int M) {
    const int wave = threadIdx.x >> 6;
    const int lane = threadIdx.x & 63;
    const int row0 = blockIdx.x * 64 + wave * 16;
    if (row0 >= M) return;
    int arow = row0 + (lane & 15);
    if (arow >= M) arow = M - 1;
    const ushort* aptr = A + (size_t)arow * C1 + (lane >> 4) * 8;
    const bf16x8* b1 = (const bf16x8*)B1;
    const bf16x8* b2 = (const bf16x8*)B2;
    f32x4 aL[4] = {}, aR[4] = {};
    #pragma unroll
    for (int kb = 0; kb < 8; ++kb) {
        bf16x8 af = *(const bf16x8*)(aptr + kb * 32);
        #pragma unroll
        for (int t = 0; t < 4; ++t)
            aL[t] = __builtin_amdgcn_mfma_f32_16x16x32_bf16(af, b1[(kb * 4 + t) * 64 + lane], aL[t], 0, 0, 0);
        #pragma unroll
        for (int t = 0; t < 4; ++t)
            aR[t] = __builtin_amdgcn_mfma_f32_16x16x32_bf16(af, b2[(kb * 4 + t) * 64 + lane], aR[t], 0, 0, 0);
    }
    const int cn = lane & 15, cq = lane >> 4;
    #pragma unroll
    for (int t = 0; t < 4; ++t) {
        float bbL = b2f(bi1[t * 16 + cn]);
        float bbR = b2f(bi2[t * 16 + cn]);
        #pragma unroll
        for (int r = 0; r < 4; ++r) {
            int grow = row0 + cq * 4 + r;
            if (grow < M) {
                // xl2/xr2 stored as fp16 (consumed by packed-f16 conv2)
                o1[(size_t)grow * HID + t * 16 + cn] = f2h(aL[t][r] + bbL);
                o2[(size_t)grow * HID + t * 16 + cn] = f2h(aR[t][r] + bbR);
            }
        }
    }
}

// ---------------- conv1: wave=node, 16-lane group=edge, all 4 heads packed f16 ----------------
// lane = 16*g + r : group g handles edge slots, lane-slot r holds channels 16r..16r+15
// Row gathers software-pipelined one iteration ahead (clamped col is always a valid node).
__global__ __launch_bounds__(256) void conv1_k(const ushort* __restrict__ xl,
                                               const ushort* __restrict__ xr,
                                               const int* __restrict__ exc,
                                               const int* __restrict__ cp,
                                               const int* __restrict__ col,
                                               const ushort* __restrict__ att,
                                               const ushort* __restrict__ bias1,
                                               const ushort* __restrict__ g1,
                                               const ushort* __restrict__ b1,
                                               const ushort* __restrict__ m1,
                                               const ushort* __restrict__ v1,
                                               ushort* __restrict__ h1out) {
    const int n = blockIdx.x * 4 + (threadIdx.x >> 6);
    if (n >= N_NODES) return;
    const int lane = threadIdx.x & 63;
    const int g = lane >> 4;                 // edge slot 0..3
    const int r = lane & 15;                 // channel slot: chans 16r..16r+15
    const uint4* xr4 = (const uint4*)(xr + (size_t)n * C1 + r * 16);
    const uint4 xru0 = xr4[0], xru1 = xr4[1];
    const uint4* at4 = (const uint4*)(att + r * 16);
    const uint4 atu0 = at4[0], atu1 = at4[1];
    h2 xrp[8], atp[8];
    xrp[0] = uh(xru0.x); xrp[1] = uh(xru0.y); xrp[2] = uh(xru0.z); xrp[3] = uh(xru0.w);
    xrp[4] = uh(xru1.x); xrp[5] = uh(xru1.y); xrp[6] = uh(xru1.z); xrp[7] = uh(xru1.w);
    atp[0] = uh(atu0.x); atp[1] = uh(atu0.y); atp[2] = uh(atu0.z); atp[3] = uh(atu0.w);
    atp[4] = uh(atu1.x); atp[5] = uh(atu1.y); atp[6] = uh(atu1.z); atp[7] = uh(atu1.w);
    const h2 ns2 = {(_Float16)NEG_SLOPE, (_Float16)NEG_SLOPE};
    const int e0 = exc[n] + cp[n >> 10];
    const int e1 = exc[n + 1] + cp[(n + 1) >> 10];
    float a[16];
    #pragma unroll
    for (int k = 0; k < 16; ++k) a[k] = 0.f;
    float den = 0.f;
    int j = e0 + g;

    auto body = [&](uint4 u0, uint4 u1, bool masked, int jm) {
        h2 xp[8];
        xp[0] = uh(u0.x); xp[1] = uh(u0.y); xp[2] = uh(u0.z); xp[3] = uh(u0.w);
        xp[4] = uh(u1.x); xp[5] = uh(u1.y); xp[6] = uh(u1.z); xp[7] = uh(u1.w);
        h2 d0 = {(_Float16)0, (_Float16)0};
        h2 d1 = {(_Float16)0, (_Float16)0};
        #pragma unroll
        for (int k = 0; k < 8; k += 2) {
            h2 t0 = xp[k] + xrp[k];
            t0 = __builtin_elementwise_max(t0, t0 * ns2);
            d0 = __builtin_elementwise_fma(t0, atp[k], d0);
            h2 t1 = xp[k + 1] + xrp[k + 1];
            t1 = __builtin_elementwise_max(t1, t1 * ns2);
            d1 = __builtin_elementwise_fma(t1, atp[k + 1], d1);
        }
        h2 ds = d0 + d1;
        float p = (float)ds.x + (float)ds.y;
        p = dpp_add<0xB1>(p);    // quad xor1
        p = dpp_add<0x4E>(p);    // quad xor2 -> per-head logit
        float w = __expf(fminf(p, 60.f));
        if (masked) w = (jm < e1) ? w : 0.f;
        den += w;
        #pragma unroll
        for (int k = 0; k < 8; ++k) {
            a[2 * k]     = fmaf(w, (float)xp[k].x, a[2 * k]);
            a[2 * k + 1] = fmaf(w, (float)xp[k].y, a[2 * k + 1]);
        }
    };
    auto rowp = [&](int s) { return (const uint4*)(xl + (size_t)(uint)s * C1 + r * 16); };

    int sA = col[j < e1 ? j : e1 - 1];
    int sB = col[j + 4 < e1 ? j + 4 : e1 - 1];
    const uint4* pA0 = rowp(sA);
    uint4 ra0 = pA0[0], ra1 = pA0[1];
    const uint4* pB0 = rowp(sB);
    uint4 rb0 = pB0[0], rb1 = pB0[1];
    int i = e0;
    for (; i + 8 <= e1; i += 8) {
        const int jn = i + g + 8;
        const int sC = col[jn < e1 ? jn : e1 - 1];
        const int sD = col[jn + 4 < e1 ? jn + 4 : e1 - 1];
        const uint4* pC = rowp(sC);            // prefetch next-iter rows
        uint4 rc0 = pC[0], rc1 = pC[1];
        const uint4* pD = rowp(sD);
        uint4 rd0 = pD[0], rd1 = pD[1];
        body(ra0, ra1, false, 0);
        body(rb0, rb1, false, 0);
        ra0 = rc0; ra1 = rc1; rb0 = rd0; rb1 = rd1;
    }
    j = i + g;
    if (i + 4 <= e1) {                       // one more full 4-edge round
        body(ra0, ra1, false, 0);
        ra0 = rb0; ra1 = rb1; i += 4; j += 4;
    }
    if (j < e1) {                            // masked tail (0..3 edges)
        body(ra0, ra1, true, j);
    }

    // reduce across the 4 edge-groups
    #pragma unroll
    for (int k = 0; k < 16; ++k) {
        a[k] += __shfl_xor(a[k], 16);
        a[k] += __shfl_xor(a[k], 32);
    }
    den += __shfl_xor(den, 16);
    den += __shfl_xor(den, 32);
    // lane (16q+r) finalizes channels 16r+4q..+3  (static select, no scratch)
    const int q = g;
    float s0 = q == 0 ? a[0] : q == 1 ? a[4] : q == 2 ? a[8]  : a[12];
    float s1 = q == 0 ? a[1] : q == 1 ? a[5] : q == 2 ? a[9]  : a[13];
    float s2 = q == 0 ? a[2] : q == 1 ? a[6] : q == 2 ? a[10] : a[14];
    float s3 = q == 0 ? a[3] : q == 1 ? a[7] : q == 2 ? a[11] : a[15];
    const int pi = r * 4 + q;                // uint2 index of 4-channel chunk
    const float inv = 1.f / den;
    const uint2 biu = ((const uint2*)bias1)[pi];
    const uint2 gu  = ((const uint2*)g1)[pi];
    const uint2 bu  = ((const uint2*)b1)[pi];
    const uint2 mu  = ((const uint2*)m1)[pi];
    const uint2 vu  = ((const uint2*)v1)[pi];
    float o0 = fmaf(s0, inv, lo16(biu.x));
    float o1 = fmaf(s1, inv, hi16(biu.x));
    float o2 = fmaf(s2, inv, lo16(biu.y));
    float o3 = fmaf(s3, inv, hi16(biu.y));
    float c0 = lo16(gu.x) * rsqrtf(lo16(vu.x) + BN_EPS);
    float c1 = hi16(gu.x) * rsqrtf(hi16(vu.x) + BN_EPS);
    float c2 = lo16(gu.y) * rsqrtf(lo16(vu.y) + BN_EPS);
    float c3 = hi16(gu.y) * rsqrtf(hi16(vu.y) + BN_EPS);
    float h0 = fmaxf((o0 - lo16(mu.x)) * c0 + lo16(bu.x), 0.f);
    float h1v = fmaxf((o1 - hi16(mu.x)) * c1 + hi16(bu.x), 0.f);
    float h2v = fmaxf((o2 - lo16(mu.y)) * c2 + lo16(bu.y), 0.f);
    float h3 = fmaxf((o3 - hi16(mu.y)) * c3 + hi16(bu.y), 0.f);
    uint2 ou;
    ou.x = (uint)f2b(h0) | ((uint)f2b(h1v) << 16);
    ou.y = (uint)f2b(h2v) | ((uint)f2b(h3) << 16);
    ((uint2*)h1out)[(size_t)n * 64 + pi] = ou;   // h1 stays bf16 (gemm2 MFMA input)
}

// ---------------- conv2 + BN2 + relu + skip + output linear (packed f16 edges) ----------------
// Row gathers software-pipelined one iteration ahead.
__global__ __launch_bounds__(256) void conv2_k(const ushort* __restrict__ xl,
                                               const ushort* __restrict__ xr,
                                               const ushort* __restrict__ xskip,
                                               const int* __restrict__ exc,
                                               const int* __restrict__ cp,
                                               const int* __restrict__ col,
                                               const ushort* __restrict__ att2,
                                               const ushort* __restrict__ bias2,
                                               const ushort* __restrict__ g2,
                                               const ushort* __restrict__ bb2,
                                               const ushort* __restrict__ m2,
                                               const ushort* __restrict__ v2,
                                               const ushort* __restrict__ Wo,
                                               const ushort* __restrict__ bo,
                                               void* __restrict__ out,
                                               const ushort* __restrict__ xraw) {
    const bool f32out = probe_f32(xraw);
    const int n = blockIdx.x * 4 + (threadIdx.x >> 6);
    if (n >= N_NODES) return;
    const int lane = threadIdx.x & 63;
    const int grp = lane >> 4;
    const uint m = lane & 15;                // uint2 index within 16-uint2 row
    const uint2* xl2v = (const uint2*)xl;
    const uint2 xru = ((const uint2*)xr)[(size_t)n * 16 + m];   // f16
    const h2 xr01 = uh(xru.x), xr23 = uh(xru.y);
    const uint2 atu = ((const uint2*)att2)[m];                  // f16
    const h2 at01 = uh(atu.x), at23 = uh(atu.y);
    const h2 ns2 = {(_Float16)NEG_SLOPE, (_Float16)NEG_SLOPE};
    const int e0 = exc[n] + cp[n >> 10];
    const int e1 = exc[n + 1] + cp[(n + 1) >> 10];
    const int deg = e1 - e0;
    const int iend = e0 + (deg & ~15);
    float a0 = 0.f, a1 = 0.f, a2 = 0.f, a3 = 0.f, den = 0.f;

    auto edge4 = [&](const uint2 xu, bool masked, int jbase) {
        const h2 x01 = uh(xu.x), x23 = uh(xu.y);
        h2 t01 = x01 + xr01;
        t01 = __builtin_elementwise_max(t01, t01 * ns2);
        h2 t23 = x23 + xr23;
        t23 = __builtin_elementwise_max(t23, t23 * ns2);
        h2 dp = __builtin_elementwise_fma(t23, at23, t01 * at01);
        float p = (float)dp.x + (float)dp.y;
        p = row16_sum(p);
        float w;
        if (masked) {
            w = __expf(fminf(p, 60.f));
            w = ((jbase + grp) < e1) ? w : 0.f;
        } else {
            w = __expf(p);   // logits bounded; no clamp in hot path
        }
        a0 = fmaf(w, (float)x01.x, a0);
        a1 = fmaf(w, (float)x01.y, a1);
        a2 = fmaf(w, (float)x23.x, a2);
        a3 = fmaf(w, (float)x23.y, a3);
        den += w;
    };

    uint s0_, s1_, s2_, s3_;
    {
        const int j0 = e0 + grp, j1 = j0 + 4, j2 = j0 + 8, j3 = j0 + 12;
        s0_ = (uint)col[j0 < e1 ? j0 : e1 - 1];
        s1_ = (uint)col[j1 < e1 ? j1 : e1 - 1];
        s2_ = (uint)col[j2 < e1 ? j2 : e1 - 1];
        s3_ = (uint)col[j3 < e1 ? j3 : e1 - 1];
    }
    // rows for the first iteration (or the tail if deg<16)
    uint2 xu0 = xl2v[(s0_ << 4) + m];
    uint2 xu1 = xl2v[(s1_ << 4) + m];
    uint2 xu2 = xl2v[(s2_ << 4) + m];
    uint2 xu3 = xl2v[(s3_ << 4) + m];
    for (int i = e0; i < iend; i += 16) {
        const int j0 = i + 16 + grp, j1 = j0 + 4, j2 = j0 + 8, j3 = j0 + 12;
        const uint t0 = (uint)col[j0 < e1 ? j0 : e1 - 1];
        const uint t1 = (uint)col[j1 < e1 ? j1 : e1 - 1];
        const uint t2 = (uint)col[j2 < e1 ? j2 : e1 - 1];
        const uint t3 = (uint)col[j3 < e1 ? j3 : e1 - 1];
        const uint2 y0 = xl2v[(t0 << 4) + m];  // prefetch next-iter rows
        const uint2 y1 = xl2v[(t1 << 4) + m];
        const uint2 y2 = xl2v[(t2 << 4) + m];
        const uint2 y3 = xl2v[(t3 << 4) + m];
        edge4(xu0, false, 0);
        edge4(xu1, false, 0);
        edge4(xu2, false, 0);
        edge4(xu3, false, 0);
        xu0 = y0; xu1 = y1; xu2 = y2; xu3 = y3;
    }
    const int rem = e1 - iend;
    if (rem > 0) {
        // rows for the tail are already in xu0..xu3
        edge4(xu0, true, iend);
        if (rem > 4)  edge4(xu1, true, iend + 4);
        if (rem > 8)  edge4(xu2, true, iend + 8);
        if (rem > 12) edge4(xu3, true, iend + 12);
    }
    a0 += __shfl_xor(a0, 16); a0 += __shfl_xor(a0, 32);
    a1 += __shfl_xor(a1, 16); a1 += __shfl_xor(a1, 32);
    a2 += __shfl_xor(a2, 16); a2 += __shfl_xor(a2, 32);
    a3 += __shfl_xor(a3, 16); a3 += __shfl_xor(a3, 32);
    den += __shfl_xor(den, 16); den += __shfl_xor(den, 32);
    if (lane < 16) {
        const float inv = 1.f / den;
        const uint2 biu = ((const uint2*)bias2)[m];
        const uint2 gu  = ((const uint2*)g2)[m];
        const uint2 bu  = ((const uint2*)bb2)[m];
        const uint2 mu  = ((const uint2*)m2)[m];
        const uint2 vu  = ((const uint2*)v2)[m];
        const uint2 sku = ((const uint2*)xskip)[(size_t)n * 16 + m];
        const uint2 wou = ((const uint2*)Wo)[m];
        float o0 = fmaf(a0, inv, lo16(biu.x));
        float o1 = fmaf(a1, inv, hi16(biu.x));
        float o2 = fmaf(a2, inv, lo16(biu.y));
        float o3 = fmaf(a3, inv, hi16(biu.y));
        float s0 = lo16(gu.x) * rsqrtf(lo16(vu.x) + BN_EPS);
        float s1 = hi16(gu.x) * rsqrtf(hi16(vu.x) + BN_EPS);
        float s2 = lo16(gu.y) * rsqrtf(lo16(vu.y) + BN_EPS);
        float s3 = hi16(gu.y) * rsqrtf(hi16(vu.y) + BN_EPS);
        float h0 = fmaxf((o0 - lo16(mu.x)) * s0 + lo16(bu.x), 0.f) + lo16(sku.x);
        float h1v = fmaxf((o1 - hi16(mu.x)) * s1 + hi16(bu.x), 0.f) + hi16(sku.x);
        float h2v = fmaxf((o2 - lo16(mu.y)) * s2 + lo16(bu.y), 0.f) + lo16(sku.y);
        float h3 = fmaxf((o3 - hi16(mu.y)) * s3 + hi16(bu.y), 0.f) + hi16(sku.y);
        float d = fmaf(h0, lo16(wou.x), fmaf(h1v, hi16(wou.x),
                  fmaf(h2v, lo16(wou.y), h3 * hi16(wou.y))));
        d = row16_sum(d);
        if (m == 0) {
            float r = d + b2f(bo[0]);
            if (f32out) ((float*)out)[n] = r;
            else        ((ushort*)out)[n] = f2b(r);
        }
    }
}

extern "C" void kernel_launch(void* const* d_in, const int* in_sizes, int n_in,
                              void* d_out, int out_size, void* d_ws, size_t ws_size,
                              hipStream_t stream) {
    char* ws = (char*)d_ws;
    size_t off = 0;
    auto alloc = [&](size_t bytes) -> void* {
        void* p = ws + off;
        off += (bytes + 255) & ~(size_t)255;
        return p;
    };
    ushort* params  = (ushort*)alloc((size_t)127617 * 2);
    int*    exc     = (int*)alloc((size_t)(N_NODES + 1) * 4);
    int*    deg     = (int*)alloc((size_t)N_NODES * 4);
    int*    epos    = (int*)alloc((size_t)EP_EDGES * 4);
    int*    colbuf  = (int*)alloc((size_t)EP_EDGES * 4);
    int*    bsum    = (int*)alloc(64 * 4);
    int*    cparr   = (int*)alloc(64 * 4);
    ushort* xl1     = (ushort*)alloc((size_t)N_NODES * C1 * 2);
    ushort* xr1     = (ushort*)alloc((size_t)N_NODES * C1 * 2);
    ushort* xskip   = (ushort*)alloc((size_t)N_NODES * HID * 2);
    ushort* h1      = (ushort*)alloc((size_t)N_NODES * C1 * 2);
    ushort* xl2     = (ushort*)alloc((size_t)N_NODES * HID * 2);
    ushort* xr2     = (ushort*)alloc((size_t)N_NODES * HID * 2);
    ushort* swzU    = (ushort*)alloc((size_t)5 * 36 * 64 * 8 * 2);   // unified Wl1|Wr1|Ws frags
    ushort* swzWl2  = (ushort*)alloc((size_t)C1 * HID * 2);
    ushort* swzWr2  = (ushort*)alloc((size_t)C1 * HID * 2);
    ushort* Abf     = (ushort*)alloc((size_t)N_NODES * IN_DIM * 2);  // x as contiguous bf16

    ushort* bl1c   = params + 40960;
    ushort* br1c   = params + 82176;
    ushort* att1c  = params + 82432;
    ushort* bias1c = params + 82688;
    ushort* g1c    = params + 82944;
    ushort* b1c    = params + 83200;
    ushort* m1c    = params + 83456;
    ushort* v1c    = params + 83712;
    ushort* bl2c   = params + 100352;
    ushort* br2c   = params + 116800;
    ushort* att2c  = params + 116864;
    ushort* bias2c = params + 116928;
    ushort* g2c    = params + 116992;
    ushort* b2c    = params + 117056;
    ushort* m2c    = params + 117120;
    ushort* v2c    = params + 117184;
    ushort* bsc    = params + 127488;
    ushort* Woc    = params + 127552;
    ushort* boc    = params + 127616;

    const int* ei_raw = (const int*)d_in[1];

    // ---- deg = 0 (needed by fused hist) ----
    (void)hipMemsetAsync(deg, 0, (size_t)N_NODES * 4, stream);

    // ---- fused front-end: swizzle+params | A->bf16 | hist(+epos) ----
    SW2 sw;
    sw.W[0] = d_in[2];  sw.D[0] = nullptr; sw.NT[0] = 16; sw.base[0] = 0;      // Wl1 -> U
    sw.W[1] = d_in[4];  sw.D[1] = nullptr; sw.NT[1] = 16; sw.base[1] = 5120;   // Wr1 -> U
    sw.W[2] = d_in[22]; sw.D[2] = nullptr; sw.NT[2] = 4;  sw.base[2] = 10240;  // Ws  -> U
    sw.W[3] = d_in[12]; sw.D[3] = swzWl2;  sw.NT[3] = 4;  sw.base[3] = 11520;  // Wl2
    sw.W[4] = d_in[14]; sw.D[4] = swzWr2;  sw.NT[4] = 4;  sw.base[4] = 13568;  // Wr2
    sw.U = swzU;
    const int spidx[19] = {3,5,6,7,8,9,10,11, 13,15,16,17,18,19,20,21, 23,24, 25};
    for (int i = 0; i < 19; ++i) sw.sp[i] = d_in[spidx[i]];
    sw.xraw = d_in[0];
    front_k<<<NB_SWZ + NB_CVT + NB_HIST, 256, 0, stream>>>(ei_raw, deg, epos, sw, params, Abf);

    const int NB_S = (N_NODES + 1023) / 1024;      // 49

    // ---- CSR scan (2 launches) ----
    scan1_k<<<NB_S, 1024, 0, stream>>>(deg, exc, bsum);
    scan2_k<<<1, 64, 0, stream>>>(bsum, cparr, exc);

    // ---- scatter (own kernel, full occupancy) ----
    scatter_k<<<NB_HIST, 256, 0, stream>>>(ei_raw, epos, exc, cparr, colbuf);

    // ---- gemm3: bf16 A + LDS-staged B ----
    gemm3_k<<<NB_RB * 4, 256, 0, stream>>>(Abf, swzU, bl1c, br1c, bsc,
                                           xl1, xr1, xskip, N_NODES);

    // ---- conv1 edge aggregation + BN1 + relu (wave=node, 4 heads packed) ----
    conv1_k<<<(N_NODES + 3) / 4, 256, 0, stream>>>(xl1, xr1, exc, cparr, colbuf,
                                                   att1c, bias1c, g1c, b1c, m1c, v1c, h1);

    // ---- layer-2 linear transforms, fused MFMA ----
    gemm2_k<<<(N_NODES + 63) / 64, 256, 0, stream>>>(h1, swzWl2, swzWr2, bl2c, br2c,
                                                     xl2, xr2, N_NODES);

    // ---- conv2 + BN2 + relu + skip + output linear ----
    conv2_k<<<(N_NODES + 3) / 4, 256, 0, stream>>>(xl2, xr2, xskip, exc, cparr, colbuf,
                                                   att2c, bias2c, g2c, b2c, m2c, v2c,
                                                   Woc, boc, d_out, (const ushort*)d_in[0]);
}

// Round 7
// 318.841 us; speedup vs baseline: 1.0236x; 1.0236x over previous
//
#include <hip/hip_runtime.h>
#include <hip/hip_bf16.h>

#define N_NODES 50000
#define E_EDGES 800000
#define EP_EDGES 850000   // E + N self loops
#define IN_DIM 160
#define HEADS 4
#define HID 64
#define C1 256            // HEADS*HID
#define NEG_SLOPE 0.2f
#define BN_EPS 1e-5f

typedef __attribute__((ext_vector_type(8))) short bf16x8;
typedef __attribute__((ext_vector_type(4))) float f32x4;
typedef _Float16 h2 __attribute__((ext_vector_type(2)));

#if __has_builtin(__builtin_amdgcn_fdot2)
#define HAS_FDOT2 1
#else
#define HAS_FDOT2 0
#endif

__device__ __forceinline__ float b2f(ushort u) {
    return __uint_as_float(((unsigned)u) << 16);
}
__device__ __forceinline__ ushort f2b(float f) {
    __hip_bfloat16 h = __float2bfloat16(f);
    return *reinterpret_cast<ushort*>(&h);
}
__device__ __forceinline__ ushort f2h(float f) {
    union { _Float16 h; ushort u; } c;
    c.h = (_Float16)f;
    return c.u;
}
__device__ __forceinline__ float lo16(uint u) { return __uint_as_float(u << 16); }
__device__ __forceinline__ float hi16(uint u) { return __uint_as_float(u & 0xffff0000u); }
__device__ __forceinline__ h2 uh(uint u) {
    union { uint u; h2 h; } c; c.u = u; return c.h;
}

// ---- in-kernel dtype probes (wave-wide, 1 read + ballot) ----
__device__ __forceinline__ bool probe_f32(const ushort* xraw) {
    int lane = threadIdx.x & 63;
    float a = fabsf(b2f(xraw[2 * lane]));
    unsigned long long m = __ballot(a > 1e-6f && a < 1e6f);
    return __popcll(m) < 48;
}
__device__ __forceinline__ bool probe_i64(const int* eraw) {
    int lane = threadIdx.x & 63;
    unsigned long long m = __ballot(eraw[2 * lane + 1] != 0);
    return __popcll(m) < 8;
}

// DPP-based add of a permuted copy: pure VALU pipe
template<int CTRL>
__device__ __forceinline__ float dpp_add(float p) {
    int t = __builtin_amdgcn_update_dpp(0, __float_as_int(p), CTRL, 0xf, 0xf, true);
    return p + __int_as_float(t);
}
// sum over each 16-lane row; all 16 lanes get the row total
__device__ __forceinline__ float row16_sum(float p) {
    p = dpp_add<0xB1>(p);    // quad_perm xor1
    p = dpp_add<0x4E>(p);    // quad_perm xor2
    p = dpp_add<0x124>(p);   // row_ror:4
    p = dpp_add<0x128>(p);   // row_ror:8
    return p;
}

// ---------------- fused front-end: weight swizzle + params | A->bf16 cvt | hist(+epos) ----------------
// deg must be zeroed (hipMemsetAsync) before this kernel.
#define NB_SWZ 62
#define NB_CVT 3907   // 1,000,000 threads x 8 elems = 8,000,000 = 50000*160
#define NB_HIST 3321

struct SW2 {
    const void* W[5];    // raw Wl1, Wr1, Ws, Wl2, Wr2
    ushort* D[5];        // D[3],D[4] used for Wl2/Wr2; D[0..2] unused (U instead)
    ushort* U;           // unified frag buffer for Wl1|Wr1|Ws: [kb][f=0..35][lane][8]
    int NT[5];
    int base[5];
    const void* sp[19];  // raw small tensors
    const void* xraw;
};

__global__ void front_k(const int* __restrict__ ei, int* __restrict__ deg,
                        int* __restrict__ epos, SW2 s, ushort* __restrict__ params,
                        ushort* __restrict__ Abf) {
    const int b = blockIdx.x;
    if (b < NB_SWZ) {
        const bool f32 = probe_f32((const ushort*)s.xraw);
        if (b < 61) {
            int idx = b * 256 + threadIdx.x;     // < 15616
            int seg = 0;
            #pragma unroll
            for (int k = 1; k < 5; ++k) seg += (idx >= s.base[k]) ? 1 : 0;
            int li = idx - s.base[seg];
            int NT = s.NT[seg];
            int N = NT << 4;
            int lane = li & 63;
            int ft = li >> 6;
            int kb = ft / NT, t = ft - kb * NT;
            int q = lane >> 4, m = lane & 15;
            const float* pf = (const float*)s.W[seg];
            const ushort* pu = (const ushort*)s.W[seg];
            ushort* d;
            if (seg < 3) {
                const int FO = (seg == 0) ? 0 : (seg == 1) ? 16 : 32;
                d = s.U + ((size_t)(kb * 36 + FO + t) * 64 + lane) * 8;
            } else {
                d = s.D[seg] + (size_t)li * 8;
            }
            #pragma unroll
            for (int j = 0; j < 8; ++j) {
                size_t src = (size_t)(kb * 32 + q * 8 + j) * N + t * 16 + m;
                d[j] = f32 ? f2b(pf[src]) : pu[src];
            }
        } else {
            const int SZ[19] = {256,256,256,256,256,256,256,256,
                                64,64,64,64,64,64,64,64,64,64, 1};
            const int OF[19] = {40960,82176,82432,82688,82944,83200,83456,83712,
                                100352,116800,116864,116928,116992,117056,117120,117184,
                                127488,127552, 127616};
            for (int e = threadIdx.x; e < 2689; e += 256) {
                int rem = e, t = 0;
                while (rem >= SZ[t]) { rem -= SZ[t]; ++t; }
                const float* pf = (const float*)s.sp[t];
                const ushort* pu = (const ushort*)s.sp[t];
                float val = f32 ? pf[rem] : b2f(pu[rem]);
                // att1 (t==2) and att2 (t==10) stored as fp16 for packed-math convs
                params[OF[t] + rem] = (t == 2 || t == 10) ? f2h(val) : f2b(val);
            }
        }
    } else if (b < NB_SWZ + NB_CVT) {
        // ---- A -> contiguous bf16 [N][160] ----
        const bool f32 = probe_f32((const ushort*)s.xraw);
        int idx = (b - NB_SWZ) * 256 + threadIdx.x;    // 16B output chunk
        if (idx < 1000000) {
            if (f32) {
                const float* px = (const float*)s.xraw + (size_t)idx * 8;
                bf16x8 r;
                #pragma unroll
                for (int j = 0; j < 8; ++j) r[j] = (short)f2b(px[j]);
                *(bf16x8*)(Abf + (size_t)idx * 8) = r;
            } else {
                *(uint4*)(Abf + (size_t)idx * 8) =
                    *(const uint4*)((const ushort*)s.xraw + (size_t)idx * 8);
            }
        }
    } else {
        const bool i64 = probe_i64(ei);
        int e = (b - NB_SWZ - NB_CVT) * 256 + threadIdx.x;
        if (e >= EP_EDGES) return;
        int dst;
        if (e < E_EDGES) {
            int idx = E_EDGES + e;
            dst = i64 ? ei[2 * idx] : ei[idx];
        } else dst = e - E_EDGES;
        epos[e] = atomicAdd(&deg[dst], 1);   // slot within node; reused by scatter
    }
}

// ---------------- block scan via wave shfl + LDS (2 barriers) ----------------
__global__ __launch_bounds__(1024) void scan1_k(const int* __restrict__ deg,
                                                int* __restrict__ exc,
                                                int* __restrict__ bsum) {
    __shared__ int wsum[16];
    const int t = threadIdx.x;
    const int lane = t & 63, w = t >> 6;
    int i = blockIdx.x * 1024 + t;
    int v = (i < N_NODES) ? deg[i] : 0;
    int sIncl = v;
    #pragma unroll
    for (int d = 1; d < 64; d <<= 1) {
        int u = __shfl_up(sIncl, d);
        if (lane >= d) sIncl += u;
    }
    if (lane == 63) wsum[w] = sIncl;
    __syncthreads();
    if (w == 0) {
        int p = (lane < 16) ? wsum[lane] : 0;
        #pragma unroll
        for (int d = 1; d < 16; d <<= 1) {
            int u = __shfl_up(p, d);
            if (lane >= d) p += u;
        }
        if (lane < 16) wsum[lane] = p;
    }
    __syncthreads();
    int base = (w > 0) ? wsum[w - 1] : 0;
    int incl = base + sIncl;
    if (i < N_NODES) exc[i] = incl - v;
    if (t == 1023) bsum[blockIdx.x] = incl;
}

// 1-wave exclusive scan of the 49 chunk sums; also closes exc[N]
__global__ void scan2_k(const int* __restrict__ bsum, int* __restrict__ cp,
                        int* __restrict__ exc) {
    int lane = threadIdx.x;   // 64
    int v = (lane < 49) ? bsum[lane] : 0;
    int orig = v;
    #pragma unroll
    for (int d = 1; d < 64; d <<= 1) {
        int u = __shfl_up(v, d);
        if (lane >= d) v += u;
    }
    if (lane < 49) cp[lane] = v - orig;               // exclusive prefix
    if (lane == 48) exc[N_NODES] = EP_EDGES - (v - orig);
}

// ---------------- scatter (atomic-free), own kernel: no LDS -> full occupancy ----------------
__global__ __launch_bounds__(256) void scatter_k(const int* __restrict__ ei,
                                                 const int* __restrict__ epos,
                                                 const int* __restrict__ exc,
                                                 const int* __restrict__ cp,
                                                 int* __restrict__ col) {
    const bool i64 = probe_i64(ei);
    int e = blockIdx.x * 256 + threadIdx.x;
    if (e >= EP_EDGES) return;
    int src, dst;
    if (e < E_EDGES) {
        if (i64) { src = ei[2 * e]; dst = ei[2 * (E_EDGES + e)]; }
        else     { src = ei[e];     dst = ei[E_EDGES + e]; }
    } else { src = e - E_EDGES; dst = src; }
    col[exc[dst] + cp[dst >> 10] + epos[e]] = src;
}

// ---------------- gemm3: bf16-A, LDS-staged B slice, 2 row-tiles/wave ----------------
// grid = 391 row-blocks (128 rows) x 4 col-groups (9 frags = 144 cols)
// LDS: cg slice of U = 9 frags x 5 kb x 1KB = 46080 B -> 3 blocks/CU
#define NB_RB 391

__global__ __launch_bounds__(256, 3) void gemm3_k(const ushort* __restrict__ Abf,
                                                  const ushort* __restrict__ U,
                                                  const ushort* __restrict__ bi1,
                                                  const ushort* __restrict__ bi2,
                                                  const ushort* __restrict__ bi3,
                                                  ushort* __restrict__ o1,
                                                  ushort* __restrict__ o2,
                                                  ushort* __restrict__ o3,
                                                  int M) {
    __shared__ ushort Bs[23040];           // 45 frags x 64 lanes x 8 ushorts = 46080 B
    const int cg = blockIdx.x & 3;
    const int rb = blockIdx.x >> 2;
    const int tid = threadIdx.x;
    // ---- stage cg slice: 2880 x 16B chunks ----
    #pragma unroll
    for (int t = 0; t < 12; ++t) {
        int c = t * 256 + tid;
        if (c < 2880) {
            int lf = c >> 6;               // local frag 0..44
            int kb = lf / 9, jj = lf - kb * 9;
            int ln = c & 63;
            *(uint4*)(Bs + (size_t)c * 8) =
                *(const uint4*)(U + ((size_t)((kb * 36 + cg * 9 + jj) * 64 + ln)) * 8);
        }
    }
    __syncthreads();
    const int wave = tid >> 6, lane = tid & 63;
    const int row0 = rb * 128 + wave * 32;
    const bool ok0 = row0 < M, ok1 = row0 + 16 < M;   // tiles 16-aligned, M%16==0
    const int car0 = ok0 ? row0 + (lane & 15) : 0;
    const int car1 = ok1 ? row0 + 16 + (lane & 15) : 0;
    const int aoff = (lane >> 4) * 8;
    f32x4 a0[9] = {}, a1[9] = {};
    #pragma unroll
    for (int kb = 0; kb < 5; ++kb) {
        bf16x8 af0 = *(const bf16x8*)(Abf + (size_t)car0 * IN_DIM + aoff + kb * 32);
        bf16x8 af1 = *(const bf16x8*)(Abf + (size_t)car1 * IN_DIM + aoff + kb * 32);
        #pragma unroll
        for (int jj = 0; jj < 9; ++jj) {
            bf16x8 bfr = *(const bf16x8*)(Bs + (size_t)((kb * 9 + jj) * 64 + lane) * 8);
            a0[jj] = __builtin_amdgcn_mfma_f32_16x16x32_bf16(af0, bfr, a0[jj], 0, 0, 0);
            a1[jj] = __builtin_amdgcn_mfma_f32_16x16x32_bf16(af1, bfr, a1[jj], 0, 0, 0);
        }
    }
    const int cn = lane & 15, cq = lane >> 4;
    #pragma unroll
    for (int rt = 0; rt < 2; ++rt) {
        const bool ok = rt ? ok1 : ok0;
        if (!ok) continue;
        const int rbase = row0 + rt * 16;
        #pragma unroll
        for (int jj = 0; jj < 9; ++jj) {
            const int f = cg * 9 + jj;
            ushort* op; int ldc, colb; const ushort* bp_; bool tobf;
            if (f < 16)      { op = o1; ldc = C1;  colb = f * 16;        bp_ = bi1 + f * 16;        tobf = false; }
            else if (f < 32) { op = o2; ldc = C1;  colb = (f - 16) * 16; bp_ = bi2 + (f - 16) * 16; tobf = false; }
            else             { op = o3; ldc = HID; colb = (f - 32) * 16; bp_ = bi3 + (f - 32) * 16; tobf = true;  }
            const float bb = b2f(bp_[cn]);
            const f32x4 av = rt ? a1[jj] : a0[jj];
            #pragma unroll
            for (int r = 0; r < 4; ++r) {
                const int grow = rbase + cq * 4 + r;
                const float v = av[r] + bb;
                op[(size_t)grow * ldc + colb + cn] = tobf ? f2b(v) : f2h(v);
            }
        }
    }
}

// ---------------- fused layer-2 MFMA GEMM: xl2(64) + xr2(64), K=256 ----------------
__global__ __launch_bounds__(256) void gemm2_k(const ushort* __restrict__ A,
                                               const ushort* __restrict__ B1,
                                               const ushort* __restrict__ B2,
                                               const ushort* __restrict__ bi1,
                                               const ushort* __restrict__ bi2,
                                               ushort* __restrict__ o1,
                                               ushort* __restrict__ o2,
                                               int M) {
    const int wave = threadIdx.x >> 6;
    const int lane = threadIdx.x & 63;
    const int row0 = blockIdx.x * 64 + wave * 16;
    if (row0 >= M) return;
    int arow = row0 + (lane & 15);
    if (arow >= M) arow = M - 1;
    const ushort* aptr = A + (size_t)arow * C1 + (lane >> 4) * 8;
    const bf16x8* b1 = (const bf16x8*)B1;
    const bf16x8* b2 = (const bf16x8*)B2;
    f32x4 aL[4] = {}, aR[4] = {};
    #pragma unroll
    for (int kb = 0; kb < 8; ++kb) {
        bf16x8 af = *(const bf16x8*)(aptr + kb * 32);
        #pragma unroll
        for (int t = 0; t < 4; ++t)
            aL[t] = __builtin_amdgcn_mfma_f32_16x16x32_bf16(af, b1[(kb * 4 + t) * 64 + lane], aL[t], 0, 0, 0);
        #pragma unroll
        for (int t = 0; t < 4; ++t)
            aR[t] = __builtin_amdgcn_mfma_f32_16x16x32_bf16(af, b2[(kb * 4 + t) * 64 + lane], aR[t], 0, 0, 0);
    }
    const int cn = lane & 15, cq = lane >> 4;
    #pragma unroll
    for (int t = 0; t < 4; ++t) {
        float bbL = b2f(bi1[t * 16 + cn]);
        float bbR = b2f(bi2[t * 16 + cn]);
        #pragma unroll
        for (int r = 0; r < 4; ++r) {
            int grow = row0 + cq * 4 + r;
            if (grow < M) {
                // xl2/xr2 stored as fp16 (consumed by packed-f16 conv2)
                o1[(size_t)grow * HID + t * 16 + cn] = f2h(aL[t][r] + bbL);
                o2[(size_t)grow * HID + t * 16 + cn] = f2h(aR[t][r] + bbR);
            }
        }
    }
}

// ---------------- conv1: wave=node, 16-lane group=edge, all 4 heads packed f16 ----------------
// lane = 16*g + r : group g handles edge slots, lane-slot r holds channels 16r..16r+15
// (head of those channels = r>>2; per-head logit reduce = 2 quad-perm DPP adds)
__global__ __launch_bounds__(256) void conv1_k(const ushort* __restrict__ xl,
                                               const ushort* __restrict__ xr,
                                               const int* __restrict__ exc,
                                               const int* __restrict__ cp,
                                               const int* __restrict__ col,
                                               const ushort* __restrict__ att,
                                               const ushort* __restrict__ bias1,
                                               const ushort* __restrict__ g1,
                                               const ushort* __restrict__ b1,
                                               const ushort* __restrict__ m1,
                                               const ushort* __restrict__ v1,
                                               ushort* __restrict__ h1out) {
    const int n = blockIdx.x * 4 + (threadIdx.x >> 6);
    if (n >= N_NODES) return;
    const int lane = threadIdx.x & 63;
    const int g = lane >> 4;                 // edge slot 0..3
    const int r = lane & 15;                 // channel slot: chans 16r..16r+15
    const uint4* xr4 = (const uint4*)(xr + (size_t)n * C1 + r * 16);
    const uint4 xru0 = xr4[0], xru1 = xr4[1];
    const uint4* at4 = (const uint4*)(att + r * 16);
    const uint4 atu0 = at4[0], atu1 = at4[1];
    h2 xrp[8], atp[8];
    xrp[0] = uh(xru0.x); xrp[1] = uh(xru0.y); xrp[2] = uh(xru0.z); xrp[3] = uh(xru0.w);
    xrp[4] = uh(xru1.x); xrp[5] = uh(xru1.y); xrp[6] = uh(xru1.z); xrp[7] = uh(xru1.w);
    atp[0] = uh(atu0.x); atp[1] = uh(atu0.y); atp[2] = uh(atu0.z); atp[3] = uh(atu0.w);
    atp[4] = uh(atu1.x); atp[5] = uh(atu1.y); atp[6] = uh(atu1.z); atp[7] = uh(atu1.w);
    const h2 ns2 = {(_Float16)NEG_SLOPE, (_Float16)NEG_SLOPE};
    const int e0 = exc[n] + cp[n >> 10];
    const int e1 = exc[n + 1] + cp[(n + 1) >> 10];
    float a[16];
    #pragma unroll
    for (int k = 0; k < 16; ++k) a[k] = 0.f;
    float den = 0.f;
    int j = e0 + g;

    auto body = [&](uint4 u0, uint4 u1, bool masked, int jm) {
        h2 xp[8];
        xp[0] = uh(u0.x); xp[1] = uh(u0.y); xp[2] = uh(u0.z); xp[3] = uh(u0.w);
        xp[4] = uh(u1.x); xp[5] = uh(u1.y); xp[6] = uh(u1.z); xp[7] = uh(u1.w);
#if HAS_FDOT2
        float p = 0.f;
        #pragma unroll
        for (int k = 0; k < 8; ++k) {
            h2 t0 = xp[k] + xrp[k];
            t0 = __builtin_elementwise_max(t0, t0 * ns2);
            p = __builtin_amdgcn_fdot2(t0, atp[k], p, false);
        }
#else
        h2 d0 = {(_Float16)0, (_Float16)0};
        h2 d1 = {(_Float16)0, (_Float16)0};
        #pragma unroll
        for (int k = 0; k < 8; k += 2) {
            h2 t0 = xp[k] + xrp[k];
            t0 = __builtin_elementwise_max(t0, t0 * ns2);
            d0 = __builtin_elementwise_fma(t0, atp[k], d0);
            h2 t1 = xp[k + 1] + xrp[k + 1];
            t1 = __builtin_elementwise_max(t1, t1 * ns2);
            d1 = __builtin_elementwise_fma(t1, atp[k + 1], d1);
        }
        h2 ds = d0 + d1;
        float p = (float)ds.x + (float)ds.y;
#endif
        p = dpp_add<0xB1>(p);    // quad xor1
        p = dpp_add<0x4E>(p);    // quad xor2 -> per-head logit
        float w = __expf(fminf(p, 60.f));
        if (masked) w = (jm < e1) ? w : 0.f;
        den += w;
        #pragma unroll
        for (int k = 0; k < 8; ++k) {
            a[2 * k]     = fmaf(w, (float)xp[k].x, a[2 * k]);
            a[2 * k + 1] = fmaf(w, (float)xp[k].y, a[2 * k + 1]);
        }
    };
    auto rowp = [&](int s) { return (const uint4*)(xl + (size_t)(uint)s * C1 + r * 16); };

    int sA = col[j < e1 ? j : e1 - 1];
    int sB = col[j + 4 < e1 ? j + 4 : e1 - 1];
    int i = e0;
    for (; i + 8 <= e1; i += 8) {
        const int jn = i + g + 8;
        int sC = col[jn < e1 ? jn : e1 - 1];
        int sD = col[jn + 4 < e1 ? jn + 4 : e1 - 1];
        const uint4* pA = rowp(sA);
        uint4 a0 = pA[0], a1 = pA[1];
        const uint4* pB = rowp(sB);
        uint4 b0 = pB[0], b1v = pB[1];
        body(a0, a1, false, 0);
        body(b0, b1v, false, 0);
        sA = sC; sB = sD;
    }
    j = i + g;
    if (i + 4 <= e1) {                       // one more full 4-edge round
        const uint4* pA = rowp(sA);
        uint4 a0 = pA[0], a1 = pA[1];
        body(a0, a1, false, 0);
        sA = sB; i += 4; j += 4;
    }
    if (j < e1) {                            // masked tail (0..3 edges)
        const uint4* pA = rowp(sA);
        uint4 a0 = pA[0], a1 = pA[1];
        body(a0, a1, true, j);
    }

    // reduce across the 4 edge-groups
    #pragma unroll
    for (int k = 0; k < 16; ++k) {
        a[k] += __shfl_xor(a[k], 16);
        a[k] += __shfl_xor(a[k], 32);
    }
    den += __shfl_xor(den, 16);
    den += __shfl_xor(den, 32);
    // lane (16q+r) finalizes channels 16r+4q..+3  (static select, no scratch)
    const int q = g;
    float s0 = q == 0 ? a[0] : q == 1 ? a[4] : q == 2 ? a[8]  : a[12];
    float s1 = q == 0 ? a[1] : q == 1 ? a[5] : q == 2 ? a[9]  : a[13];
    float s2 = q == 0 ? a[2] : q == 1 ? a[6] : q == 2 ? a[10] : a[14];
    float s3 = q == 0 ? a[3] : q == 1 ? a[7] : q == 2 ? a[11] : a[15];
    const int pi = r * 4 + q;                // uint2 index of 4-channel chunk
    const float inv = 1.f / den;
    const uint2 biu = ((const uint2*)bias1)[pi];
    const uint2 gu  = ((const uint2*)g1)[pi];
    const uint2 bu  = ((const uint2*)b1)[pi];
    const uint2 mu  = ((const uint2*)m1)[pi];
    const uint2 vu  = ((const uint2*)v1)[pi];
    float o0 = fmaf(s0, inv, lo16(biu.x));
    float o1 = fmaf(s1, inv, hi16(biu.x));
    float o2 = fmaf(s2, inv, lo16(biu.y));
    float o3 = fmaf(s3, inv, hi16(biu.y));
    float c0 = lo16(gu.x) * rsqrtf(lo16(vu.x) + BN_EPS);
    float c1 = hi16(gu.x) * rsqrtf(hi16(vu.x) + BN_EPS);
    float c2 = lo16(gu.y) * rsqrtf(lo16(vu.y) + BN_EPS);
    float c3 = hi16(gu.y) * rsqrtf(hi16(vu.y) + BN_EPS);
    float h0 = fmaxf((o0 - lo16(mu.x)) * c0 + lo16(bu.x), 0.f);
    float h1v = fmaxf((o1 - hi16(mu.x)) * c1 + hi16(bu.x), 0.f);
    float h2v = fmaxf((o2 - lo16(mu.y)) * c2 + lo16(bu.y), 0.f);
    float h3 = fmaxf((o3 - hi16(mu.y)) * c3 + hi16(bu.y), 0.f);
    uint2 ou;
    ou.x = (uint)f2b(h0) | ((uint)f2b(h1v) << 16);
    ou.y = (uint)f2b(h2v) | ((uint)f2b(h3) << 16);
    ((uint2*)h1out)[(size_t)n * 64 + pi] = ou;   // h1 stays bf16 (gemm2 MFMA input)
}

// ---------------- conv2 + BN2 + relu + skip + output linear (packed f16 edges) ----------------
__global__ __launch_bounds__(256) void conv2_k(const ushort* __restrict__ xl,
                                               const ushort* __restrict__ xr,
                                               const ushort* __restrict__ xskip,
                                               const int* __restrict__ exc,
                                               const int* __restrict__ cp,
                                               const int* __restrict__ col,
                                               const ushort* __restrict__ att2,
                                               const ushort* __restrict__ bias2,
                                               const ushort* __restrict__ g2,
                                               const ushort* __restrict__ bb2,
                                               const ushort* __restrict__ m2,
                                               const ushort* __restrict__ v2,
                                               const ushort* __restrict__ Wo,
                                               const ushort* __restrict__ bo,
                                               void* __restrict__ out,
                                               const ushort* __restrict__ xraw) {
    const bool f32out = probe_f32(xraw);
    const int n = blockIdx.x * 4 + (threadIdx.x >> 6);
    if (n >= N_NODES) return;
    const int lane = threadIdx.x & 63;
    const int grp = lane >> 4;
    const uint m = lane & 15;                // uint2 index within 16-uint2 row
    const uint2* xl2v = (const uint2*)xl;
    const uint2 xru = ((const uint2*)xr)[(size_t)n * 16 + m];   // f16
    const h2 xr01 = uh(xru.x), xr23 = uh(xru.y);
    const uint2 atu = ((const uint2*)att2)[m];                  // f16
    const h2 at01 = uh(atu.x), at23 = uh(atu.y);
    const h2 ns2 = {(_Float16)NEG_SLOPE, (_Float16)NEG_SLOPE};
    const int e0 = exc[n] + cp[n >> 10];
    const int e1 = exc[n + 1] + cp[(n + 1) >> 10];
    const int deg = e1 - e0;
    const int iend = e0 + (deg & ~15);
    float a0 = 0.f, a1 = 0.f, a2 = 0.f, a3 = 0.f, den = 0.f;

    auto edge4 = [&](const uint2 xu, bool masked, int jbase) {
        const h2 x01 = uh(xu.x), x23 = uh(xu.y);
        h2 t01 = x01 + xr01;
        t01 = __builtin_elementwise_max(t01, t01 * ns2);
        h2 t23 = x23 + xr23;
        t23 = __builtin_elementwise_max(t23, t23 * ns2);
#if HAS_FDOT2
        float p = __builtin_amdgcn_fdot2(t01, at01, 0.f, false);
        p = __builtin_amdgcn_fdot2(t23, at23, p, false);
#else
        h2 dp = __builtin_elementwise_fma(t23, at23, t01 * at01);
        float p = (float)dp.x + (float)dp.y;
#endif
        p = row16_sum(p);
        float w;
        if (masked) {
            w = __expf(fminf(p, 60.f));
            w = ((jbase + grp) < e1) ? w : 0.f;
        } else {
            w = __expf(p);   // logits bounded; no clamp in hot path
        }
        a0 = fmaf(w, (float)x01.x, a0);
        a1 = fmaf(w, (float)x01.y, a1);
        a2 = fmaf(w, (float)x23.x, a2);
        a3 = fmaf(w, (float)x23.y, a3);
        den += w;
    };

    uint s0_, s1_, s2_, s3_;
    {
        const int j0 = e0 + grp, j1 = j0 + 4, j2 = j0 + 8, j3 = j0 + 12;
        s0_ = (uint)col[j0 < e1 ? j0 : e1 - 1];
        s1_ = (uint)col[j1 < e1 ? j1 : e1 - 1];
        s2_ = (uint)col[j2 < e1 ? j2 : e1 - 1];
        s3_ = (uint)col[j3 < e1 ? j3 : e1 - 1];
    }
    for (int i = e0; i < iend; i += 16) {
        const uint2 xu0 = xl2v[(s0_ << 4) + m];
        const uint2 xu1 = xl2v[(s1_ << 4) + m];
        const uint2 xu2 = xl2v[(s2_ << 4) + m];
        const uint2 xu3 = xl2v[(s3_ << 4) + m];
        const int j0 = i + 16 + grp, j1 = j0 + 4, j2 = j0 + 8, j3 = j0 + 12;
        s0_ = (uint)col[j0 < e1 ? j0 : e1 - 1];
        s1_ = (uint)col[j1 < e1 ? j1 : e1 - 1];
        s2_ = (uint)col[j2 < e1 ? j2 : e1 - 1];
        s3_ = (uint)col[j3 < e1 ? j3 : e1 - 1];
        edge4(xu0, false, 0);
        edge4(xu1, false, 0);
        edge4(xu2, false, 0);
        edge4(xu3, false, 0);
    }
    const int rem = e1 - iend;
    if (rem > 0) {
        const uint2 xu0 = xl2v[(s0_ << 4) + m];
        const uint2 xu1 = xl2v[(s1_ << 4) + m];
        const uint2 xu2 = xl2v[(s2_ << 4) + m];
        const uint2 xu3 = xl2v[(s3_ << 4) + m];
        edge4(xu0, true, iend);
        if (rem > 4)  edge4(xu1, true, iend + 4);
        if (rem > 8)  edge4(xu2, true, iend + 8);
        if (rem > 12) edge4(xu3, true, iend + 12);
    }
    a0 += __shfl_xor(a0, 16); a0 += __shfl_xor(a0, 32);
    a1 += __shfl_xor(a1, 16); a1 += __shfl_xor(a1, 32);
    a2 += __shfl_xor(a2, 16); a2 += __shfl_xor(a2, 32);
    a3 += __shfl_xor(a3, 16); a3 += __shfl_xor(a3, 32);
    den += __shfl_xor(den, 16); den += __shfl_xor(den, 32);
    if (lane < 16) {
        const float inv = 1.f / den;
        const uint2 biu = ((const uint2*)bias2)[m];
        const uint2 gu  = ((const uint2*)g2)[m];
        const uint2 bu  = ((const uint2*)bb2)[m];
        const uint2 mu  = ((const uint2*)m2)[m];
        const uint2 vu  = ((const uint2*)v2)[m];
        const uint2 sku = ((const uint2*)xskip)[(size_t)n * 16 + m];
        const uint2 wou = ((const uint2*)Wo)[m];
        float o0 = fmaf(a0, inv, lo16(biu.x));
        float o1 = fmaf(a1, inv, hi16(biu.x));
        float o2 = fmaf(a2, inv, lo16(biu.y));
        float o3 = fmaf(a3, inv, hi16(biu.y));
        float s0 = lo16(gu.x) * rsqrtf(lo16(vu.x) + BN_EPS);
        float s1 = hi16(gu.x) * rsqrtf(hi16(vu.x) + BN_EPS);
        float s2 = lo16(gu.y) * rsqrtf(lo16(vu.y) + BN_EPS);
        float s3 = hi16(gu.y) * rsqrtf(hi16(vu.y) + BN_EPS);
        float h0 = fmaxf((o0 - lo16(mu.x)) * s0 + lo16(bu.x), 0.f) + lo16(sku.x);
        float h1v = fmaxf((o1 - hi16(mu.x)) * s1 + hi16(bu.x), 0.f) + hi16(sku.x);
        float h2v = fmaxf((o2 - lo16(mu.y)) * s2 + lo16(bu.y), 0.f) + lo16(sku.y);
        float h3 = fmaxf((o3 - hi16(mu.y)) * s3 + hi16(bu.y), 0.f) + hi16(sku.y);
        float d = fmaf(h0, lo16(wou.x), fmaf(h1v, hi16(wou.x),
                  fmaf(h2v, lo16(wou.y), h3 * hi16(wou.y))));
        d = row16_sum(d);
        if (m == 0) {
            float r = d + b2f(bo[0]);
            if (f32out) ((float*)out)[n] = r;
            else        ((ushort*)out)[n] = f2b(r);
        }
    }
}

extern "C" void kernel_launch(void* const* d_in, const int* in_sizes, int n_in,
                              void* d_out, int out_size, void* d_ws, size_t ws_size,
                              hipStream_t stream) {
    char* ws = (char*)d_ws;
    size_t off = 0;
    auto alloc = [&](size_t bytes) -> void* {
        void* p = ws + off;
        off += (bytes + 255) & ~(size_t)255;
        return p;
    };
    ushort* params  = (ushort*)alloc((size_t)127617 * 2);
    int*    exc     = (int*)alloc((size_t)(N_NODES + 1) * 4);
    int*    deg     = (int*)alloc((size_t)N_NODES * 4);
    int*    epos    = (int*)alloc((size_t)EP_EDGES * 4);
    int*    colbuf  = (int*)alloc((size_t)EP_EDGES * 4);
    int*    bsum    = (int*)alloc(64 * 4);
    int*    cparr   = (int*)alloc(64 * 4);
    ushort* xl1     = (ushort*)alloc((size_t)N_NODES * C1 * 2);
    ushort* xr1     = (ushort*)alloc((size_t)N_NODES * C1 * 2);
    ushort* xskip   = (ushort*)alloc((size_t)N_NODES * HID * 2);
    ushort* h1      = (ushort*)alloc((size_t)N_NODES * C1 * 2);
    ushort* xl2     = (ushort*)alloc((size_t)N_NODES * HID * 2);
    ushort* xr2     = (ushort*)alloc((size_t)N_NODES * HID * 2);
    ushort* swzU    = (ushort*)alloc((size_t)5 * 36 * 64 * 8 * 2);   // unified Wl1|Wr1|Ws frags
    ushort* swzWl2  = (ushort*)alloc((size_t)C1 * HID * 2);
    ushort* swzWr2  = (ushort*)alloc((size_t)C1 * HID * 2);
    ushort* Abf     = (ushort*)alloc((size_t)N_NODES * IN_DIM * 2);  // x as contiguous bf16

    ushort* bl1c   = params + 40960;
    ushort* br1c   = params + 82176;
    ushort* att1c  = params + 82432;
    ushort* bias1c = params + 82688;
    ushort* g1c    = params + 82944;
    ushort* b1c    = params + 83200;
    ushort* m1c    = params + 83456;
    ushort* v1c    = params + 83712;
    ushort* bl2c   = params + 100352;
    ushort* br2c   = params + 116800;
    ushort* att2c  = params + 116864;
    ushort* bias2c = params + 116928;
    ushort* g2c    = params + 116992;
    ushort* b2c    = params + 117056;
    ushort* m2c    = params + 117120;
    ushort* v2c    = params + 117184;
    ushort* bsc    = params + 127488;
    ushort* Woc    = params + 127552;
    ushort* boc    = params + 127616;

    const int* ei_raw = (const int*)d_in[1];

    // ---- deg = 0 (needed by fused hist) ----
    (void)hipMemsetAsync(deg, 0, (size_t)N_NODES * 4, stream);

    // ---- fused front-end: swizzle+params | A->bf16 | hist(+epos) ----
    SW2 sw;
    sw.W[0] = d_in[2];  sw.D[0] = nullptr; sw.NT[0] = 16; sw.base[0] = 0;      // Wl1 -> U
    sw.W[1] = d_in[4];  sw.D[1] = nullptr; sw.NT[1] = 16; sw.base[1] = 5120;   // Wr1 -> U
    sw.W[2] = d_in[22]; sw.D[2] = nullptr; sw.NT[2] = 4;  sw.base[2] = 10240;  // Ws  -> U
    sw.W[3] = d_in[12]; sw.D[3] = swzWl2;  sw.NT[3] = 4;  sw.base[3] = 11520;  // Wl2
    sw.W[4] = d_in[14]; sw.D[4] = swzWr2;  sw.NT[4] = 4;  sw.base[4] = 13568;  // Wr2
    sw.U = swzU;
    const int spidx[19] = {3,5,6,7,8,9,10,11, 13,15,16,17,18,19,20,21, 23,24, 25};
    for (int i = 0; i < 19; ++i) sw.sp[i] = d_in[spidx[i]];
    sw.xraw = d_in[0];
    front_k<<<NB_SWZ + NB_CVT + NB_HIST, 256, 0, stream>>>(ei_raw, deg, epos, sw, params, Abf);

    const int NB_S = (N_NODES + 1023) / 1024;      // 49

    // ---- CSR scan (2 launches) ----
    scan1_k<<<NB_S, 1024, 0, stream>>>(deg, exc, bsum);
    scan2_k<<<1, 64, 0, stream>>>(bsum, cparr, exc);

    // ---- scatter (own kernel, full occupancy) ----
    scatter_k<<<NB_HIST, 256, 0, stream>>>(ei_raw, epos, exc, cparr, colbuf);

    // ---- gemm3: bf16 A + LDS-staged B ----
    gemm3_k<<<NB_RB * 4, 256, 0, stream>>>(Abf, swzU, bl1c, br1c, bsc,
                                           xl1, xr1, xskip, N_NODES);

    // ---- conv1 edge aggregation + BN1 + relu (wave=node, 4 heads packed) ----
    conv1_k<<<(N_NODES + 3) / 4, 256, 0, stream>>>(xl1, xr1, exc, cparr, colbuf,
                                                   att1c, bias1c, g1c, b1c, m1c, v1c, h1);

    // ---- layer-2 linear transforms, fused MFMA ----
    gemm2_k<<<(N_NODES + 63) / 64, 256, 0, stream>>>(h1, swzWl2, swzWr2, bl2c, br2c,
                                                     xl2, xr2, N_NODES);

    // ---- conv2 + BN2 + relu + skip + output linear ----
    conv2_k<<<(N_NODES + 3) / 4, 256, 0, stream>>>(xl2, xr2, xskip, exc, cparr, colbuf,
                                                   att2c, bias2c, g2c, b2c, m2c, v2c,
                                                   Woc, boc, d_out, (const ushort*)d_in[0]);
}

// Round 8
// 317.648 us; speedup vs baseline: 1.0274x; 1.0038x over previous
//
#include <hip/hip_runtime.h>
#include <hip/hip_bf16.h>

#define N_NODES 50000
#define E_EDGES 800000
#define EP_EDGES 850000   // E + N self loops
#define IN_DIM 160
#define HEADS 4
#define HID 64
#define C1 256            // HEADS*HID
#define NEG_SLOPE 0.2f
#define BN_EPS 1e-5f

typedef __attribute__((ext_vector_type(8))) short bf16x8;
typedef __attribute__((ext_vector_type(4))) float f32x4;
typedef _Float16 h2 __attribute__((ext_vector_type(2)));

#if __has_builtin(__builtin_amdgcn_fdot2)
#define HAS_FDOT2 1
#else
#define HAS_FDOT2 0
#endif

__device__ __forceinline__ float b2f(ushort u) {
    return __uint_as_float(((unsigned)u) << 16);
}
__device__ __forceinline__ ushort f2b(float f) {
    __hip_bfloat16 h = __float2bfloat16(f);
    return *reinterpret_cast<ushort*>(&h);
}
__device__ __forceinline__ ushort f2h(float f) {
    union { _Float16 h; ushort u; } c;
    c.h = (_Float16)f;
    return c.u;
}
__device__ __forceinline__ float lo16(uint u) { return __uint_as_float(u << 16); }
__device__ __forceinline__ float hi16(uint u) { return __uint_as_float(u & 0xffff0000u); }
__device__ __forceinline__ h2 uh(uint u) {
    union { uint u; h2 h; } c; c.u = u; return c.h;
}

// ---- in-kernel dtype probes (wave-wide, 1 read + ballot) ----
__device__ __forceinline__ bool probe_f32(const ushort* xraw) {
    int lane = threadIdx.x & 63;
    float a = fabsf(b2f(xraw[2 * lane]));
    unsigned long long m = __ballot(a > 1e-6f && a < 1e6f);
    return __popcll(m) < 48;
}
__device__ __forceinline__ bool probe_i64(const int* eraw) {
    int lane = threadIdx.x & 63;
    unsigned long long m = __ballot(eraw[2 * lane + 1] != 0);
    return __popcll(m) < 8;
}

// DPP-based add of a permuted copy: pure VALU pipe
template<int CTRL>
__device__ __forceinline__ float dpp_add(float p) {
    int t = __builtin_amdgcn_update_dpp(0, __float_as_int(p), CTRL, 0xf, 0xf, true);
    return p + __int_as_float(t);
}
// sum over each 16-lane row; all 16 lanes get the row total
__device__ __forceinline__ float row16_sum(float p) {
    p = dpp_add<0xB1>(p);    // quad_perm xor1
    p = dpp_add<0x4E>(p);    // quad_perm xor2
    p = dpp_add<0x124>(p);   // row_ror:4
    p = dpp_add<0x128>(p);   // row_ror:8
    return p;
}

// ---------------- fused front-end: weight swizzle + params | A->bf16 cvt | hist(+epos) ----------------
// deg must be zeroed (hipMemsetAsync) before this kernel.
#define NB_SWZ 62
#define NB_CVT 3907   // 1,000,000 threads x 8 elems = 8,000,000 = 50000*160
#define NB_HIST 3321

struct SW2 {
    const void* W[5];    // raw Wl1, Wr1, Ws, Wl2, Wr2
    ushort* D[5];        // D[3],D[4] used for Wl2/Wr2; D[0..2] unused (U instead)
    ushort* U;           // unified frag buffer for Wl1|Wr1|Ws: [kb][f=0..35][lane][8]
    int NT[5];
    int base[5];
    const void* sp[19];  // raw small tensors
    const void* xraw;
};

__global__ void front_k(const int* __restrict__ ei, int* __restrict__ deg,
                        int* __restrict__ epos, SW2 s, ushort* __restrict__ params,
                        ushort* __restrict__ Abf) {
    const int b = blockIdx.x;
    if (b < NB_SWZ) {
        const bool f32 = probe_f32((const ushort*)s.xraw);
        if (b < 61) {
            int idx = b * 256 + threadIdx.x;     // < 15616
            int seg = 0;
            #pragma unroll
            for (int k = 1; k < 5; ++k) seg += (idx >= s.base[k]) ? 1 : 0;
            int li = idx - s.base[seg];
            int NT = s.NT[seg];
            int N = NT << 4;
            int lane = li & 63;
            int ft = li >> 6;
            int kb = ft / NT, t = ft - kb * NT;
            int q = lane >> 4, m = lane & 15;
            const float* pf = (const float*)s.W[seg];
            const ushort* pu = (const ushort*)s.W[seg];
            ushort* d;
            if (seg < 3) {
                const int FO = (seg == 0) ? 0 : (seg == 1) ? 16 : 32;
                d = s.U + ((size_t)(kb * 36 + FO + t) * 64 + lane) * 8;
            } else {
                d = s.D[seg] + (size_t)li * 8;
            }
            #pragma unroll
            for (int j = 0; j < 8; ++j) {
                size_t src = (size_t)(kb * 32 + q * 8 + j) * N + t * 16 + m;
                d[j] = f32 ? f2b(pf[src]) : pu[src];
            }
        } else {
            const int SZ[19] = {256,256,256,256,256,256,256,256,
                                64,64,64,64,64,64,64,64,64,64, 1};
            const int OF[19] = {40960,82176,82432,82688,82944,83200,83456,83712,
                                100352,116800,116864,116928,116992,117056,117120,117184,
                                127488,127552, 127616};
            for (int e = threadIdx.x; e < 2689; e += 256) {
                int rem = e, t = 0;
                while (rem >= SZ[t]) { rem -= SZ[t]; ++t; }
                const float* pf = (const float*)s.sp[t];
                const ushort* pu = (const ushort*)s.sp[t];
                float val = f32 ? pf[rem] : b2f(pu[rem]);
                // att1 (t==2) and att2 (t==10) stored as fp16 for packed-math convs
                params[OF[t] + rem] = (t == 2 || t == 10) ? f2h(val) : f2b(val);
            }
        }
    } else if (b < NB_SWZ + NB_CVT) {
        // ---- A -> contiguous bf16 [N][160] ----
        const bool f32 = probe_f32((const ushort*)s.xraw);
        int idx = (b - NB_SWZ) * 256 + threadIdx.x;    // 16B output chunk
        if (idx < 1000000) {
            if (f32) {
                const float* px = (const float*)s.xraw + (size_t)idx * 8;
                bf16x8 r;
                #pragma unroll
                for (int j = 0; j < 8; ++j) r[j] = (short)f2b(px[j]);
                *(bf16x8*)(Abf + (size_t)idx * 8) = r;
            } else {
                *(uint4*)(Abf + (size_t)idx * 8) =
                    *(const uint4*)((const ushort*)s.xraw + (size_t)idx * 8);
            }
        }
    } else {
        const bool i64 = probe_i64(ei);
        int e = (b - NB_SWZ - NB_CVT) * 256 + threadIdx.x;
        if (e >= EP_EDGES) return;
        int dst;
        if (e < E_EDGES) {
            int idx = E_EDGES + e;
            dst = i64 ? ei[2 * idx] : ei[idx];
        } else dst = e - E_EDGES;
        epos[e] = atomicAdd(&deg[dst], 1);   // slot within node; reused by scatter
    }
}

// ---------------- block scan via wave shfl + LDS (2 barriers) ----------------
__global__ __launch_bounds__(1024) void scan1_k(const int* __restrict__ deg,
                                                int* __restrict__ exc,
                                                int* __restrict__ bsum) {
    __shared__ int wsum[16];
    const int t = threadIdx.x;
    const int lane = t & 63, w = t >> 6;
    int i = blockIdx.x * 1024 + t;
    int v = (i < N_NODES) ? deg[i] : 0;
    int sIncl = v;
    #pragma unroll
    for (int d = 1; d < 64; d <<= 1) {
        int u = __shfl_up(sIncl, d);
        if (lane >= d) sIncl += u;
    }
    if (lane == 63) wsum[w] = sIncl;
    __syncthreads();
    if (w == 0) {
        int p = (lane < 16) ? wsum[lane] : 0;
        #pragma unroll
        for (int d = 1; d < 16; d <<= 1) {
            int u = __shfl_up(p, d);
            if (lane >= d) p += u;
        }
        if (lane < 16) wsum[lane] = p;
    }
    __syncthreads();
    int base = (w > 0) ? wsum[w - 1] : 0;
    int incl = base + sIncl;
    if (i < N_NODES) exc[i] = incl - v;
    if (t == 1023) bsum[blockIdx.x] = incl;
}

// 1-wave exclusive scan of the 49 chunk sums; also closes exc[N]
__global__ void scan2_k(const int* __restrict__ bsum, int* __restrict__ cp,
                        int* __restrict__ exc) {
    int lane = threadIdx.x;   // 64
    int v = (lane < 49) ? bsum[lane] : 0;
    int orig = v;
    #pragma unroll
    for (int d = 1; d < 64; d <<= 1) {
        int u = __shfl_up(v, d);
        if (lane >= d) v += u;
    }
    if (lane < 49) cp[lane] = v - orig;               // exclusive prefix
    if (lane == 48) exc[N_NODES] = EP_EDGES - (v - orig);
}

// ---------------- scatter (atomic-free), own kernel: no LDS -> full occupancy ----------------
__global__ __launch_bounds__(256) void scatter_k(const int* __restrict__ ei,
                                                 const int* __restrict__ epos,
                                                 const int* __restrict__ exc,
                                                 const int* __restrict__ cp,
                                                 int* __restrict__ col) {
    const bool i64 = probe_i64(ei);
    int e = blockIdx.x * 256 + threadIdx.x;
    if (e >= EP_EDGES) return;
    int src, dst;
    if (e < E_EDGES) {
        if (i64) { src = ei[2 * e]; dst = ei[2 * (E_EDGES + e)]; }
        else     { src = ei[e];     dst = ei[E_EDGES + e]; }
    } else { src = e - E_EDGES; dst = src; }
    col[exc[dst] + cp[dst >> 10] + epos[e]] = src;
}

// ---------------- gemm3: bf16-A, per-kb double-buffered LDS B, 2 row-tiles/wave ----------------
// grid = 391 row-blocks (128 rows) x 4 col-groups (9 frags = 144 cols)
// LDS: 2 x (9 frags x 1KB) = 18432 B -> LDS allows 8 blocks/CU; VGPR(~107) -> 4 blocks/CU
#define NB_RB 391

__global__ __launch_bounds__(256, 4) void gemm3_k(const ushort* __restrict__ Abf,
                                                  const ushort* __restrict__ U,
                                                  const ushort* __restrict__ bi1,
                                                  const ushort* __restrict__ bi2,
                                                  const ushort* __restrict__ bi3,
                                                  ushort* __restrict__ o1,
                                                  ushort* __restrict__ o2,
                                                  ushort* __restrict__ o3,
                                                  int M) {
    __shared__ ushort Bs[2][4608];         // per-kb: 9 frags x 64 lanes x 8 ushorts = 9216 B
    const int cg = blockIdx.x & 3;
    const int rb = blockIdx.x >> 2;
    const int tid = threadIdx.x;
    auto stage = [&](int kb, int buf) {
        // 576 x 16B chunks; 256 threads -> 2 full rounds + 64
        #pragma unroll
        for (int t = 0; t < 3; ++t) {
            int c = t * 256 + tid;
            if (c < 576) {
                *(uint4*)(&Bs[buf][(size_t)c * 8]) =
                    *(const uint4*)(U + ((size_t)((kb * 36 + cg * 9 + (c >> 6)) * 64 + (c & 63))) * 8);
            }
        }
    };
    const int wave = tid >> 6, lane = tid & 63;
    const int row0 = rb * 128 + wave * 32;
    const bool ok0 = row0 < M, ok1 = row0 + 16 < M;   // tiles 16-aligned, M%16==0
    const int car0 = ok0 ? row0 + (lane & 15) : 0;
    const int car1 = ok1 ? row0 + 16 + (lane & 15) : 0;
    const int aoff = (lane >> 4) * 8;
    f32x4 a0[9] = {}, a1[9] = {};
    stage(0, 0);
    __syncthreads();
    for (int kb = 0; kb < 5; ++kb) {
        const int buf = kb & 1;
        if (kb < 4) stage(kb + 1, buf ^ 1);      // overlap next-kb staging with this kb's MFMAs
        bf16x8 af0 = *(const bf16x8*)(Abf + (size_t)car0 * IN_DIM + aoff + kb * 32);
        bf16x8 af1 = *(const bf16x8*)(Abf + (size_t)car1 * IN_DIM + aoff + kb * 32);
        #pragma unroll
        for (int jj = 0; jj < 9; ++jj) {
            bf16x8 bfr = *(const bf16x8*)(&Bs[buf][(size_t)(jj * 64 + lane) * 8]);
            a0[jj] = __builtin_amdgcn_mfma_f32_16x16x32_bf16(af0, bfr, a0[jj], 0, 0, 0);
            a1[jj] = __builtin_amdgcn_mfma_f32_16x16x32_bf16(af1, bfr, a1[jj], 0, 0, 0);
        }
        __syncthreads();
    }
    const int cn = lane & 15, cq = lane >> 4;
    #pragma unroll
    for (int rt = 0; rt < 2; ++rt) {
        const bool ok = rt ? ok1 : ok0;
        if (!ok) continue;
        const int rbase = row0 + rt * 16;
        #pragma unroll
        for (int jj = 0; jj < 9; ++jj) {
            const int f = cg * 9 + jj;
            ushort* op; int ldc, colb; const ushort* bp_; bool tobf;
            if (f < 16)      { op = o1; ldc = C1;  colb = f * 16;        bp_ = bi1 + f * 16;        tobf = false; }
            else if (f < 32) { op = o2; ldc = C1;  colb = (f - 16) * 16; bp_ = bi2 + (f - 16) * 16; tobf = false; }
            else             { op = o3; ldc = HID; colb = (f - 32) * 16; bp_ = bi3 + (f - 32) * 16; tobf = true;  }
            const float bb = b2f(bp_[cn]);
            const f32x4 av = rt ? a1[jj] : a0[jj];
            #pragma unroll
            for (int r = 0; r < 4; ++r) {
                const int grow = rbase + cq * 4 + r;
                const float v = av[r] + bb;
                op[(size_t)grow * ldc + colb + cn] = tobf ? f2b(v) : f2h(v);
            }
        }
    }
}

// ---------------- fused layer-2 MFMA GEMM: xl2(64) + xr2(64), K=256 ----------------
__global__ __launch_bounds__(256) void gemm2_k(const ushort* __restrict__ A,
                                               const ushort* __restrict__ B1,
                                               const ushort* __restrict__ B2,
                                               const ushort* __restrict__ bi1,
                                               const ushort* __restrict__ bi2,
                                               ushort* __restrict__ o1,
                                               ushort* __restrict__ o2,
                                               int M) {
    const int wave = threadIdx.x >> 6;
    const int lane = threadIdx.x & 63;
    const int row0 = blockIdx.x * 64 + wave * 16;
    if (row0 >= M) return;
    int arow = row0 + (lane & 15);
    if (arow >= M) arow = M - 1;
    const ushort* aptr = A + (size_t)arow * C1 + (lane >> 4) * 8;
    const bf16x8* b1 = (const bf16x8*)B1;
    const bf16x8* b2 = (const bf16x8*)B2;
    f32x4 aL[4] = {}, aR[4] = {};
    #pragma unroll
    for (int kb = 0; kb < 8; ++kb) {
        bf16x8 af = *(const bf16x8*)(aptr + kb * 32);
        #pragma unroll
        for (int t = 0; t < 4; ++t)
            aL[t] = __builtin_amdgcn_mfma_f32_16x16x32_bf16(af, b1[(kb * 4 + t) * 64 + lane], aL[t], 0, 0, 0);
        #pragma unroll
        for (int t = 0; t < 4; ++t)
            aR[t] = __builtin_amdgcn_mfma_f32_16x16x32_bf16(af, b2[(kb * 4 + t) * 64 + lane], aR[t], 0, 0, 0);
    }
    const int cn = lane & 15, cq = lane >> 4;
    #pragma unroll
    for (int t = 0; t < 4; ++t) {
        float bbL = b2f(bi1[t * 16 + cn]);
        float bbR = b2f(bi2[t * 16 + cn]);
        #pragma unroll
        for (int r = 0; r < 4; ++r) {
            int grow = row0 + cq * 4 + r;
            if (grow < M) {
                // xl2/xr2 stored as fp16 (consumed by packed-f16 conv2)
                o1[(size_t)grow * HID + t * 16 + cn] = f2h(aL[t][r] + bbL);
                o2[(size_t)grow * HID + t * 16 + cn] = f2h(aR[t][r] + bbR);
            }
        }
    }
}

// ---------------- conv1: wave=node, 16-lane group=edge, all 4 heads packed f16 ----------------
// lane = 16*g + r : group g handles edge slots, lane-slot r holds channels 16r..16r+15
// (head of those channels = r>>2; per-head logit reduce = 2 quad-perm DPP adds)
__global__ __launch_bounds__(256) void conv1_k(const ushort* __restrict__ xl,
                                               const ushort* __restrict__ xr,
                                               const int* __restrict__ exc,
                                               const int* __restrict__ cp,
                                               const int* __restrict__ col,
                                               const ushort* __restrict__ att,
                                               const ushort* __restrict__ bias1,
                                               const ushort* __restrict__ g1,
                                               const ushort* __restrict__ b1,
                                               const ushort* __restrict__ m1,
                                               const ushort* __restrict__ v1,
                                               ushort* __restrict__ h1out) {
    const int n = blockIdx.x * 4 + (threadIdx.x >> 6);
    if (n >= N_NODES) return;
    const int lane = threadIdx.x & 63;
    const int g = lane >> 4;                 // edge slot 0..3
    const int r = lane & 15;                 // channel slot: chans 16r..16r+15
    const uint4* xr4 = (const uint4*)(xr + (size_t)n * C1 + r * 16);
    const uint4 xru0 = xr4[0], xru1 = xr4[1];
    const uint4* at4 = (const uint4*)(att + r * 16);
    const uint4 atu0 = at4[0], atu1 = at4[1];
    h2 xrp[8], atp[8];
    xrp[0] = uh(xru0.x); xrp[1] = uh(xru0.y); xrp[2] = uh(xru0.z); xrp[3] = uh(xru0.w);
    xrp[4] = uh(xru1.x); xrp[5] = uh(xru1.y); xrp[6] = uh(xru1.z); xrp[7] = uh(xru1.w);
    atp[0] = uh(atu0.x); atp[1] = uh(atu0.y); atp[2] = uh(atu0.z); atp[3] = uh(atu0.w);
    atp[4] = uh(atu1.x); atp[5] = uh(atu1.y); atp[6] = uh(atu1.z); atp[7] = uh(atu1.w);
    const h2 ns2 = {(_Float16)NEG_SLOPE, (_Float16)NEG_SLOPE};
    const int e0 = exc[n] + cp[n >> 10];
    const int e1 = exc[n + 1] + cp[(n + 1) >> 10];
    float a[16];
    #pragma unroll
    for (int k = 0; k < 16; ++k) a[k] = 0.f;
    float den = 0.f;
    int j = e0 + g;

    auto body = [&](uint4 u0, uint4 u1, bool masked, int jm) {
        h2 xp[8];
        xp[0] = uh(u0.x); xp[1] = uh(u0.y); xp[2] = uh(u0.z); xp[3] = uh(u0.w);
        xp[4] = uh(u1.x); xp[5] = uh(u1.y); xp[6] = uh(u1.z); xp[7] = uh(u1.w);
#if HAS_FDOT2
        float p = 0.f;
        #pragma unroll
        for (int k = 0; k < 8; ++k) {
            h2 t0 = xp[k] + xrp[k];
            t0 = __builtin_elementwise_max(t0, t0 * ns2);
            p = __builtin_amdgcn_fdot2(t0, atp[k], p, false);
        }
#else
        h2 d0 = {(_Float16)0, (_Float16)0};
        h2 d1 = {(_Float16)0, (_Float16)0};
        #pragma unroll
        for (int k = 0; k < 8; k += 2) {
            h2 t0 = xp[k] + xrp[k];
            t0 = __builtin_elementwise_max(t0, t0 * ns2);
            d0 = __builtin_elementwise_fma(t0, atp[k], d0);
            h2 t1 = xp[k + 1] + xrp[k + 1];
            t1 = __builtin_elementwise_max(t1, t1 * ns2);
            d1 = __builtin_elementwise_fma(t1, atp[k + 1], d1);
        }
        h2 ds = d0 + d1;
        float p = (float)ds.x + (float)ds.y;
#endif
        p = dpp_add<0xB1>(p);    // quad xor1
        p = dpp_add<0x4E>(p);    // quad xor2 -> per-head logit
        float w = __expf(fminf(p, 60.f));
        if (masked) w = (jm < e1) ? w : 0.f;
        den += w;
        #pragma unroll
        for (int k = 0; k < 8; ++k) {
            a[2 * k]     = fmaf(w, (float)xp[k].x, a[2 * k]);
            a[2 * k + 1] = fmaf(w, (float)xp[k].y, a[2 * k + 1]);
        }
    };
    auto rowp = [&](int s) { return (const uint4*)(xl + (size_t)(uint)s * C1 + r * 16); };

    int sA = col[j < e1 ? j : e1 - 1];
    int sB = col[j + 4 < e1 ? j + 4 : e1 - 1];
    int i = e0;
    for (; i + 8 <= e1; i += 8) {
        const int jn = i + g + 8;
        int sC = col[jn < e1 ? jn : e1 - 1];
        int sD = col[jn + 4 < e1 ? jn + 4 : e1 - 1];
        const uint4* pA = rowp(sA);
        uint4 a0 = pA[0], a1 = pA[1];
        const uint4* pB = rowp(sB);
        uint4 b0 = pB[0], b1v = pB[1];
        body(a0, a1, false, 0);
        body(b0, b1v, false, 0);
        sA = sC; sB = sD;
    }
    j = i + g;
    if (i + 4 <= e1) {                       // one more full 4-edge round
        const uint4* pA = rowp(sA);
        uint4 a0 = pA[0], a1 = pA[1];
        body(a0, a1, false, 0);
        sA = sB; i += 4; j += 4;
    }
    if (j < e1) {                            // masked tail (0..3 edges)
        const uint4* pA = rowp(sA);
        uint4 a0 = pA[0], a1 = pA[1];
        body(a0, a1, true, j);
    }

    // reduce across the 4 edge-groups
    #pragma unroll
    for (int k = 0; k < 16; ++k) {
        a[k] += __shfl_xor(a[k], 16);
        a[k] += __shfl_xor(a[k], 32);
    }
    den += __shfl_xor(den, 16);
    den += __shfl_xor(den, 32);
    // lane (16q+r) finalizes channels 16r+4q..+3  (static select, no scratch)
    const int q = g;
    float s0 = q == 0 ? a[0] : q == 1 ? a[4] : q == 2 ? a[8]  : a[12];
    float s1 = q == 0 ? a[1] : q == 1 ? a[5] : q == 2 ? a[9]  : a[13];
    float s2 = q == 0 ? a[2] : q == 1 ? a[6] : q == 2 ? a[10] : a[14];
    float s3 = q == 0 ? a[3] : q == 1 ? a[7] : q == 2 ? a[11] : a[15];
    const int pi = r * 4 + q;                // uint2 index of 4-channel chunk
    const float inv = 1.f / den;
    const uint2 biu = ((const uint2*)bias1)[pi];
    const uint2 gu  = ((const uint2*)g1)[pi];
    const uint2 bu  = ((const uint2*)b1)[pi];
    const uint2 mu  = ((const uint2*)m1)[pi];
    const uint2 vu  = ((const uint2*)v1)[pi];
    float o0 = fmaf(s0, inv, lo16(biu.x));
    float o1 = fmaf(s1, inv, hi16(biu.x));
    float o2 = fmaf(s2, inv, lo16(biu.y));
    float o3 = fmaf(s3, inv, hi16(biu.y));
    float c0 = lo16(gu.x) * rsqrtf(lo16(vu.x) + BN_EPS);
    float c1 = hi16(gu.x) * rsqrtf(hi16(vu.x) + BN_EPS);
    float c2 = lo16(gu.y) * rsqrtf(lo16(vu.y) + BN_EPS);
    float c3 = hi16(gu.y) * rsqrtf(hi16(vu.y) + BN_EPS);
    float h0 = fmaxf((o0 - lo16(mu.x)) * c0 + lo16(bu.x), 0.f);
    float h1v = fmaxf((o1 - hi16(mu.x)) * c1 + hi16(bu.x), 0.f);
    float h2v = fmaxf((o2 - lo16(mu.y)) * c2 + lo16(bu.y), 0.f);
    float h3 = fmaxf((o3 - hi16(mu.y)) * c3 + hi16(bu.y), 0.f);
    uint2 ou;
    ou.x = (uint)f2b(h0) | ((uint)f2b(h1v) << 16);
    ou.y = (uint)f2b(h2v) | ((uint)f2b(h3) << 16);
    ((uint2*)h1out)[(size_t)n * 64 + pi] = ou;   // h1 stays bf16 (gemm2 MFMA input)
}

// ---------------- conv2 + BN2 + relu + skip + output linear (packed f16 edges) ----------------
__global__ __launch_bounds__(256) void conv2_k(const ushort* __restrict__ xl,
                                               const ushort* __restrict__ xr,
                                               const ushort* __restrict__ xskip,
                                               const int* __restrict__ exc,
                                               const int* __restrict__ cp,
                                               const int* __restrict__ col,
                                               const ushort* __restrict__ att2,
                                               const ushort* __restrict__ bias2,
                                               const ushort* __restrict__ g2,
                                               const ushort* __restrict__ bb2,
                                               const ushort* __restrict__ m2,
                                               const ushort* __restrict__ v2,
                                               const ushort* __restrict__ Wo,
                                               const ushort* __restrict__ bo,
                                               void* __restrict__ out,
                                               const ushort* __restrict__ xraw) {
    const bool f32out = probe_f32(xraw);
    const int n = blockIdx.x * 4 + (threadIdx.x >> 6);
    if (n >= N_NODES) return;
    const int lane = threadIdx.x & 63;
    const int grp = lane >> 4;
    const uint m = lane & 15;                // uint2 index within 16-uint2 row
    const uint2* xl2v = (const uint2*)xl;
    const uint2 xru = ((const uint2*)xr)[(size_t)n * 16 + m];   // f16
    const h2 xr01 = uh(xru.x), xr23 = uh(xru.y);
    const uint2 atu = ((const uint2*)att2)[m];                  // f16
    const h2 at01 = uh(atu.x), at23 = uh(atu.y);
    const h2 ns2 = {(_Float16)NEG_SLOPE, (_Float16)NEG_SLOPE};
    const int e0 = exc[n] + cp[n >> 10];
    const int e1 = exc[n + 1] + cp[(n + 1) >> 10];
    const int deg = e1 - e0;
    const int iend = e0 + (deg & ~15);
    float a0 = 0.f, a1 = 0.f, a2 = 0.f, a3 = 0.f, den = 0.f;

    auto edge4 = [&](const uint2 xu, bool masked, int jbase) {
        const h2 x01 = uh(xu.x), x23 = uh(xu.y);
        h2 t01 = x01 + xr01;
        t01 = __builtin_elementwise_max(t01, t01 * ns2);
        h2 t23 = x23 + xr23;
        t23 = __builtin_elementwise_max(t23, t23 * ns2);
#if HAS_FDOT2
        float p = __builtin_amdgcn_fdot2(t01, at01, 0.f, false);
        p = __builtin_amdgcn_fdot2(t23, at23, p, false);
#else
        h2 dp = __builtin_elementwise_fma(t23, at23, t01 * at01);
        float p = (float)dp.x + (float)dp.y;
#endif
        p = row16_sum(p);
        float w;
        if (masked) {
            w = __expf(fminf(p, 60.f));
            w = ((jbase + grp) < e1) ? w : 0.f;
        } else {
            w = __expf(p);   // logits bounded; no clamp in hot path
        }
        a0 = fmaf(w, (float)x01.x, a0);
        a1 = fmaf(w, (float)x01.y, a1);
        a2 = fmaf(w, (float)x23.x, a2);
        a3 = fmaf(w, (float)x23.y, a3);
        den += w;
    };

    uint s0_, s1_, s2_, s3_;
    {
        const int j0 = e0 + grp, j1 = j0 + 4, j2 = j0 + 8, j3 = j0 + 12;
        s0_ = (uint)col[j0 < e1 ? j0 : e1 - 1];
        s1_ = (uint)col[j1 < e1 ? j1 : e1 - 1];
        s2_ = (uint)col[j2 < e1 ? j2 : e1 - 1];
        s3_ = (uint)col[j3 < e1 ? j3 : e1 - 1];
    }
    for (int i = e0; i < iend; i += 16) {
        const uint2 xu0 = xl2v[(s0_ << 4) + m];
        const uint2 xu1 = xl2v[(s1_ << 4) + m];
        const uint2 xu2 = xl2v[(s2_ << 4) + m];
        const uint2 xu3 = xl2v[(s3_ << 4) + m];
        const int j0 = i + 16 + grp, j1 = j0 + 4, j2 = j0 + 8, j3 = j0 + 12;
        s0_ = (uint)col[j0 < e1 ? j0 : e1 - 1];
        s1_ = (uint)col[j1 < e1 ? j1 : e1 - 1];
        s2_ = (uint)col[j2 < e1 ? j2 : e1 - 1];
        s3_ = (uint)col[j3 < e1 ? j3 : e1 - 1];
        edge4(xu0, false, 0);
        edge4(xu1, false, 0);
        edge4(xu2, false, 0);
        edge4(xu3, false, 0);
    }
    const int rem = e1 - iend;
    if (rem > 0) {
        const uint2 xu0 = xl2v[(s0_ << 4) + m];
        const uint2 xu1 = xl2v[(s1_ << 4) + m];
        const uint2 xu2 = xl2v[(s2_ << 4) + m];
        const uint2 xu3 = xl2v[(s3_ << 4) + m];
        edge4(xu0, true, iend);
        if (rem > 4)  edge4(xu1, true, iend + 4);
        if (rem > 8)  edge4(xu2, true, iend + 8);
        if (rem > 12) edge4(xu3, true, iend + 12);
    }
    a0 += __shfl_xor(a0, 16); a0 += __shfl_xor(a0, 32);
    a1 += __shfl_xor(a1, 16); a1 += __shfl_xor(a1, 32);
    a2 += __shfl_xor(a2, 16); a2 += __shfl_xor(a2, 32);
    a3 += __shfl_xor(a3, 16); a3 += __shfl_xor(a3, 32);
    den += __shfl_xor(den, 16); den += __shfl_xor(den, 32);
    if (lane < 16) {
        const float inv = 1.f / den;
        const uint2 biu = ((const uint2*)bias2)[m];
        const uint2 gu  = ((const uint2*)g2)[m];
        const uint2 bu  = ((const uint2*)bb2)[m];
        const uint2 mu  = ((const uint2*)m2)[m];
        const uint2 vu  = ((const uint2*)v2)[m];
        const uint2 sku = ((const uint2*)xskip)[(size_t)n * 16 + m];
        const uint2 wou = ((const uint2*)Wo)[m];
        float o0 = fmaf(a0, inv, lo16(biu.x));
        float o1 = fmaf(a1, inv, hi16(biu.x));
        float o2 = fmaf(a2, inv, lo16(biu.y));
        float o3 = fmaf(a3, inv, hi16(biu.y));
        float s0 = lo16(gu.x) * rsqrtf(lo16(vu.x) + BN_EPS);
        float s1 = hi16(gu.x) * rsqrtf(hi16(vu.x) + BN_EPS);
        float s2 = lo16(gu.y) * rsqrtf(lo16(vu.y) + BN_EPS);
        float s3 = hi16(gu.y) * rsqrtf(hi16(vu.y) + BN_EPS);
        float h0 = fmaxf((o0 - lo16(mu.x)) * s0 + lo16(bu.x), 0.f) + lo16(sku.x);
        float h1v = fmaxf((o1 - hi16(mu.x)) * s1 + hi16(bu.x), 0.f) + hi16(sku.x);
        float h2v = fmaxf((o2 - lo16(mu.y)) * s2 + lo16(bu.y), 0.f) + lo16(sku.y);
        float h3 = fmaxf((o3 - hi16(mu.y)) * s3 + hi16(bu.y), 0.f) + hi16(sku.y);
        float d = fmaf(h0, lo16(wou.x), fmaf(h1v, hi16(wou.x),
                  fmaf(h2v, lo16(wou.y), h3 * hi16(wou.y))));
        d = row16_sum(d);
        if (m == 0) {
            float r = d + b2f(bo[0]);
            if (f32out) ((float*)out)[n] = r;
            else        ((ushort*)out)[n] = f2b(r);
        }
    }
}

extern "C" void kernel_launch(void* const* d_in, const int* in_sizes, int n_in,
                              void* d_out, int out_size, void* d_ws, size_t ws_size,
                              hipStream_t stream) {
    char* ws = (char*)d_ws;
    size_t off = 0;
    auto alloc = [&](size_t bytes) -> void* {
        void* p = ws + off;
        off += (bytes + 255) & ~(size_t)255;
        return p;
    };
    ushort* params  = (ushort*)alloc((size_t)127617 * 2);
    int*    exc     = (int*)alloc((size_t)(N_NODES + 1) * 4);
    int*    deg     = (int*)alloc((size_t)N_NODES * 4);
    int*    epos    = (int*)alloc((size_t)EP_EDGES * 4);
    int*    colbuf  = (int*)alloc((size_t)EP_EDGES * 4);
    int*    bsum    = (int*)alloc(64 * 4);
    int*    cparr   = (int*)alloc(64 * 4);
    ushort* xl1     = (ushort*)alloc((size_t)N_NODES * C1 * 2);
    ushort* xr1     = (ushort*)alloc((size_t)N_NODES * C1 * 2);
    ushort* xskip   = (ushort*)alloc((size_t)N_NODES * HID * 2);
    ushort* h1      = (ushort*)alloc((size_t)N_NODES * C1 * 2);
    ushort* xl2     = (ushort*)alloc((size_t)N_NODES * HID * 2);
    ushort* xr2     = (ushort*)alloc((size_t)N_NODES * HID * 2);
    ushort* swzU    = (ushort*)alloc((size_t)5 * 36 * 64 * 8 * 2);   // unified Wl1|Wr1|Ws frags
    ushort* swzWl2  = (ushort*)alloc((size_t)C1 * HID * 2);
    ushort* swzWr2  = (ushort*)alloc((size_t)C1 * HID * 2);
    ushort* Abf     = (ushort*)alloc((size_t)N_NODES * IN_DIM * 2);  // x as contiguous bf16

    ushort* bl1c   = params + 40960;
    ushort* br1c   = params + 82176;
    ushort* att1c  = params + 82432;
    ushort* bias1c = params + 82688;
    ushort* g1c    = params + 82944;
    ushort* b1c    = params + 83200;
    ushort* m1c    = params + 83456;
    ushort* v1c    = params + 83712;
    ushort* bl2c   = params + 100352;
    ushort* br2c   = params + 116800;
    ushort* att2c  = params + 116864;
    ushort* bias2c = params + 116928;
    ushort* g2c    = params + 116992;
    ushort* b2c    = params + 117056;
    ushort* m2c    = params + 117120;
    ushort* v2c    = params + 117184;
    ushort* bsc    = params + 127488;
    ushort* Woc    = params + 127552;
    ushort* boc    = params + 127616;

    const int* ei_raw = (const int*)d_in[1];

    // ---- deg = 0 (needed by fused hist) ----
    (void)hipMemsetAsync(deg, 0, (size_t)N_NODES * 4, stream);

    // ---- fused front-end: swizzle+params | A->bf16 | hist(+epos) ----
    SW2 sw;
    sw.W[0] = d_in[2];  sw.D[0] = nullptr; sw.NT[0] = 16; sw.base[0] = 0;      // Wl1 -> U
    sw.W[1] = d_in[4];  sw.D[1] = nullptr; sw.NT[1] = 16; sw.base[1] = 5120;   // Wr1 -> U
    sw.W[2] = d_in[22]; sw.D[2] = nullptr; sw.NT[2] = 4;  sw.base[2] = 10240;  // Ws  -> U
    sw.W[3] = d_in[12]; sw.D[3] = swzWl2;  sw.NT[3] = 4;  sw.base[3] = 11520;  // Wl2
    sw.W[4] = d_in[14]; sw.D[4] = swzWr2;  sw.NT[4] = 4;  sw.base[4] = 13568;  // Wr2
    sw.U = swzU;
    const int spidx[19] = {3,5,6,7,8,9,10,11, 13,15,16,17,18,19,20,21, 23,24, 25};
    for (int i = 0; i < 19; ++i) sw.sp[i] = d_in[spidx[i]];
    sw.xraw = d_in[0];
    front_k<<<NB_SWZ + NB_CVT + NB_HIST, 256, 0, stream>>>(ei_raw, deg, epos, sw, params, Abf);

    const int NB_S = (N_NODES + 1023) / 1024;      // 49

    // ---- CSR scan (2 launches) ----
    scan1_k<<<NB_S, 1024, 0, stream>>>(deg, exc, bsum);
    scan2_k<<<1, 64, 0, stream>>>(bsum, cparr, exc);

    // ---- scatter (own kernel, full occupancy) ----
    scatter_k<<<NB_HIST, 256, 0, stream>>>(ei_raw, epos, exc, cparr, colbuf);

    // ---- gemm3: bf16 A + per-kb double-buffered LDS B ----
    gemm3_k<<<NB_RB * 4, 256, 0, stream>>>(Abf, swzU, bl1c, br1c, bsc,
                                           xl1, xr1, xskip, N_NODES);

    // ---- conv1 edge aggregation + BN1 + relu (wave=node, 4 heads packed) ----
    conv1_k<<<(N_NODES + 3) / 4, 256, 0, stream>>>(xl1, xr1, exc, cparr, colbuf,
                                                   att1c, bias1c, g1c, b1c, m1c, v1c, h1);

    // ---- layer-2 linear transforms, fused MFMA ----
    gemm2_k<<<(N_NODES + 63) / 64, 256, 0, stream>>>(h1, swzWl2, swzWr2, bl2c, br2c,
                                                     xl2, xr2, N_NODES);

    // ---- conv2 + BN2 + relu + skip + output linear ----
    conv2_k<<<(N_NODES + 3) / 4, 256, 0, stream>>>(xl2, xr2, xskip, exc, cparr, colbuf,
                                                   att2c, bias2c, g2c, b2c, m2c, v2c,
                                                   Woc, boc, d_out, (const ushort*)d_in[0]);
}

// Round 9
// 311.749 us; speedup vs baseline: 1.0469x; 1.0189x over previous
//
#include <hip/hip_runtime.h>
#include <hip/hip_bf16.h>

#define N_NODES 50000
#define E_EDGES 800000
#define EP_EDGES 850000   // E + N self loops
#define IN_DIM 160
#define HEADS 4
#define HID 64
#define C1 256            // HEADS*HID
#define NEG_SLOPE 0.2f
#define BN_EPS 1e-5f

typedef __attribute__((ext_vector_type(8))) short bf16x8;
typedef __attribute__((ext_vector_type(4))) float f32x4;
typedef _Float16 h2 __attribute__((ext_vector_type(2)));

#if __has_builtin(__builtin_amdgcn_fdot2)
#define HAS_FDOT2 1
#else
#define HAS_FDOT2 0
#endif

__device__ __forceinline__ float b2f(ushort u) {
    return __uint_as_float(((unsigned)u) << 16);
}
__device__ __forceinline__ ushort f2b(float f) {
    __hip_bfloat16 h = __float2bfloat16(f);
    return *reinterpret_cast<ushort*>(&h);
}
__device__ __forceinline__ ushort f2h(float f) {
    union { _Float16 h; ushort u; } c;
    c.h = (_Float16)f;
    return c.u;
}
__device__ __forceinline__ float lo16(uint u) { return __uint_as_float(u << 16); }
__device__ __forceinline__ float hi16(uint u) { return __uint_as_float(u & 0xffff0000u); }
__device__ __forceinline__ h2 uh(uint u) {
    union { uint u; h2 h; } c; c.u = u; return c.h;
}

// ---- in-kernel dtype probes (wave-wide, 1 read + ballot) ----
__device__ __forceinline__ bool probe_f32(const ushort* xraw) {
    int lane = threadIdx.x & 63;
    float a = fabsf(b2f(xraw[2 * lane]));
    unsigned long long m = __ballot(a > 1e-6f && a < 1e6f);
    return __popcll(m) < 48;
}
__device__ __forceinline__ bool probe_i64(const int* eraw) {
    int lane = threadIdx.x & 63;
    unsigned long long m = __ballot(eraw[2 * lane + 1] != 0);
    return __popcll(m) < 8;
}

// DPP-based add of a permuted copy: pure VALU pipe
template<int CTRL>
__device__ __forceinline__ float dpp_add(float p) {
    int t = __builtin_amdgcn_update_dpp(0, __float_as_int(p), CTRL, 0xf, 0xf, true);
    return p + __int_as_float(t);
}
// sum over each 16-lane row; all 16 lanes get the row total
__device__ __forceinline__ float row16_sum(float p) {
    p = dpp_add<0xB1>(p);    // quad_perm xor1
    p = dpp_add<0x4E>(p);    // quad_perm xor2
    p = dpp_add<0x124>(p);   // row_ror:4
    p = dpp_add<0x128>(p);   // row_ror:8
    return p;
}

// ---------------- fused front-end: weight swizzle + params | A->bf16 cvt | hist(+epos) ----------------
// deg must be zeroed (hipMemsetAsync) before this kernel.
#define NB_SWZ 62
#define NB_CVT 3907   // 1,000,000 threads x 8 elems = 8,000,000 = 50000*160
#define NB_HIST 3321

struct SW2 {
    const void* W[5];    // raw Wl1, Wr1, Ws, Wl2, Wr2
    ushort* D[5];        // D[3],D[4] used for Wl2/Wr2; D[0..2] unused (U instead)
    ushort* U;           // unified frag buffer for Wl1|Wr1|Ws: [kb][f=0..35][lane][8]
    int NT[5];
    int base[5];
    const void* sp[19];  // raw small tensors
    const void* xraw;
};

__global__ void front_k(const int* __restrict__ ei, int* __restrict__ deg,
                        int* __restrict__ epos, SW2 s, ushort* __restrict__ params,
                        ushort* __restrict__ Abf) {
    const int b = blockIdx.x;
    if (b < NB_SWZ) {
        const bool f32 = probe_f32((const ushort*)s.xraw);
        if (b < 61) {
            int idx = b * 256 + threadIdx.x;     // < 15616
            int seg = 0;
            #pragma unroll
            for (int k = 1; k < 5; ++k) seg += (idx >= s.base[k]) ? 1 : 0;
            int li = idx - s.base[seg];
            int NT = s.NT[seg];
            int N = NT << 4;
            int lane = li & 63;
            int ft = li >> 6;
            int kb = ft / NT, t = ft - kb * NT;
            int q = lane >> 4, m = lane & 15;
            const float* pf = (const float*)s.W[seg];
            const ushort* pu = (const ushort*)s.W[seg];
            ushort* d;
            if (seg < 3) {
                const int FO = (seg == 0) ? 0 : (seg == 1) ? 16 : 32;
                d = s.U + ((size_t)(kb * 36 + FO + t) * 64 + lane) * 8;
            } else {
                d = s.D[seg] + (size_t)li * 8;
            }
            #pragma unroll
            for (int j = 0; j < 8; ++j) {
                size_t src = (size_t)(kb * 32 + q * 8 + j) * N + t * 16 + m;
                d[j] = f32 ? f2b(pf[src]) : pu[src];
            }
        } else {
            const int SZ[19] = {256,256,256,256,256,256,256,256,
                                64,64,64,64,64,64,64,64,64,64, 1};
            const int OF[19] = {40960,82176,82432,82688,82944,83200,83456,83712,
                                100352,116800,116864,116928,116992,117056,117120,117184,
                                127488,127552, 127616};
            for (int e = threadIdx.x; e < 2689; e += 256) {
                int rem = e, t = 0;
                while (rem >= SZ[t]) { rem -= SZ[t]; ++t; }
                const float* pf = (const float*)s.sp[t];
                const ushort* pu = (const ushort*)s.sp[t];
                float val = f32 ? pf[rem] : b2f(pu[rem]);
                // att1 (t==2) and att2 (t==10) stored as fp16 for packed-math convs
                params[OF[t] + rem] = (t == 2 || t == 10) ? f2h(val) : f2b(val);
            }
        }
    } else if (b < NB_SWZ + NB_CVT) {
        // ---- A -> contiguous bf16 [N][160] ----
        const bool f32 = probe_f32((const ushort*)s.xraw);
        int idx = (b - NB_SWZ) * 256 + threadIdx.x;    // 16B output chunk
        if (idx < 1000000) {
            if (f32) {
                const float* px = (const float*)s.xraw + (size_t)idx * 8;
                bf16x8 r;
                #pragma unroll
                for (int j = 0; j < 8; ++j) r[j] = (short)f2b(px[j]);
                *(bf16x8*)(Abf + (size_t)idx * 8) = r;
            } else {
                *(uint4*)(Abf + (size_t)idx * 8) =
                    *(const uint4*)((const ushort*)s.xraw + (size_t)idx * 8);
            }
        }
    } else {
        const bool i64 = probe_i64(ei);
        int e = (b - NB_SWZ - NB_CVT) * 256 + threadIdx.x;
        if (e >= EP_EDGES) return;
        int dst;
        if (e < E_EDGES) {
            int idx = E_EDGES + e;
            dst = i64 ? ei[2 * idx] : ei[idx];
        } else dst = e - E_EDGES;
        epos[e] = atomicAdd(&deg[dst], 1);   // slot within node; reused by scatter
    }
}

// ---------------- block scan via wave shfl + LDS (2 barriers) ----------------
__global__ __launch_bounds__(1024) void scan1_k(const int* __restrict__ deg,
                                                int* __restrict__ exc,
                                                int* __restrict__ bsum) {
    __shared__ int wsum[16];
    const int t = threadIdx.x;
    const int lane = t & 63, w = t >> 6;
    int i = blockIdx.x * 1024 + t;
    int v = (i < N_NODES) ? deg[i] : 0;
    int sIncl = v;
    #pragma unroll
    for (int d = 1; d < 64; d <<= 1) {
        int u = __shfl_up(sIncl, d);
        if (lane >= d) sIncl += u;
    }
    if (lane == 63) wsum[w] = sIncl;
    __syncthreads();
    if (w == 0) {
        int p = (lane < 16) ? wsum[lane] : 0;
        #pragma unroll
        for (int d = 1; d < 16; d <<= 1) {
            int u = __shfl_up(p, d);
            if (lane >= d) p += u;
        }
        if (lane < 16) wsum[lane] = p;
    }
    __syncthreads();
    int base = (w > 0) ? wsum[w - 1] : 0;
    int incl = base + sIncl;
    if (i < N_NODES) exc[i] = incl - v;
    if (t == 1023) bsum[blockIdx.x] = incl;
}

// 1-wave exclusive scan of the 49 chunk sums; also closes exc[N]
__global__ void scan2_k(const int* __restrict__ bsum, int* __restrict__ cp,
                        int* __restrict__ exc) {
    int lane = threadIdx.x;   // 64
    int v = (lane < 49) ? bsum[lane] : 0;
    int orig = v;
    #pragma unroll
    for (int d = 1; d < 64; d <<= 1) {
        int u = __shfl_up(v, d);
        if (lane >= d) v += u;
    }
    if (lane < 49) cp[lane] = v - orig;               // exclusive prefix
    if (lane == 48) exc[N_NODES] = EP_EDGES - (v - orig);
}

// ---------------- fused: gemm3 (blocks 0..1563) | scatter (blocks 1564..4884) ----------------
// gemm3: bf16-A, per-kb double-buffered LDS B, 2 row-tiles/wave
// grid = 391 row-blocks (128 rows) x 4 col-groups (9 frags = 144 cols), then 3321 scatter blocks
// LDS: 2 x (9 frags x 1KB) = 18432 B -> 8 blocks/CU (scatter blocks exit before LDS use)
#define NB_RB 391
#define NB_G3F (NB_RB * 4)

__global__ __launch_bounds__(256, 4) void gemm3_k(const ushort* __restrict__ Abf,
                                                  const ushort* __restrict__ U,
                                                  const ushort* __restrict__ bi1,
                                                  const ushort* __restrict__ bi2,
                                                  const ushort* __restrict__ bi3,
                                                  ushort* __restrict__ o1,
                                                  ushort* __restrict__ o2,
                                                  ushort* __restrict__ o3,
                                                  int M,
                                                  const int* __restrict__ ei,
                                                  const int* __restrict__ epos,
                                                  const int* __restrict__ exc,
                                                  const int* __restrict__ cp,
                                                  int* __restrict__ col) {
    __shared__ ushort Bs[2][4608];         // per-kb: 9 frags x 64 lanes x 8 ushorts = 9216 B
    if (blockIdx.x >= NB_G3F) {
        // ---- scatter (atomic-free), overlapped with gemm3 blocks ----
        const bool i64 = probe_i64(ei);
        int e = (blockIdx.x - NB_G3F) * 256 + threadIdx.x;
        if (e >= EP_EDGES) return;
        int src, dst;
        if (e < E_EDGES) {
            if (i64) { src = ei[2 * e]; dst = ei[2 * (E_EDGES + e)]; }
            else     { src = ei[e];     dst = ei[E_EDGES + e]; }
        } else { src = e - E_EDGES; dst = src; }
        col[exc[dst] + cp[dst >> 10] + epos[e]] = src;
        return;
    }
    const int cg = blockIdx.x & 3;
    const int rb = blockIdx.x >> 2;
    const int tid = threadIdx.x;
    auto stage = [&](int kb, int buf) {
        // 576 x 16B chunks; 256 threads -> 2 full rounds + 64
        #pragma unroll
        for (int t = 0; t < 3; ++t) {
            int c = t * 256 + tid;
            if (c < 576) {
                *(uint4*)(&Bs[buf][(size_t)c * 8]) =
                    *(const uint4*)(U + ((size_t)((kb * 36 + cg * 9 + (c >> 6)) * 64 + (c & 63))) * 8);
            }
        }
    };
    const int wave = tid >> 6, lane = tid & 63;
    const int row0 = rb * 128 + wave * 32;
    const bool ok0 = row0 < M, ok1 = row0 + 16 < M;   // tiles 16-aligned, M%16==0
    const int car0 = ok0 ? row0 + (lane & 15) : 0;
    const int car1 = ok1 ? row0 + 16 + (lane & 15) : 0;
    const int aoff = (lane >> 4) * 8;
    f32x4 a0[9] = {}, a1[9] = {};
    stage(0, 0);
    __syncthreads();
    for (int kb = 0; kb < 5; ++kb) {
        const int buf = kb & 1;
        if (kb < 4) stage(kb + 1, buf ^ 1);      // overlap next-kb staging with this kb's MFMAs
        bf16x8 af0 = *(const bf16x8*)(Abf + (size_t)car0 * IN_DIM + aoff + kb * 32);
        bf16x8 af1 = *(const bf16x8*)(Abf + (size_t)car1 * IN_DIM + aoff + kb * 32);
        #pragma unroll
        for (int jj = 0; jj < 9; ++jj) {
            bf16x8 bfr = *(const bf16x8*)(&Bs[buf][(size_t)(jj * 64 + lane) * 8]);
            a0[jj] = __builtin_amdgcn_mfma_f32_16x16x32_bf16(af0, bfr, a0[jj], 0, 0, 0);
            a1[jj] = __builtin_amdgcn_mfma_f32_16x16x32_bf16(af1, bfr, a1[jj], 0, 0, 0);
        }
        __syncthreads();
    }
    const int cn = lane & 15, cq = lane >> 4;
    #pragma unroll
    for (int rt = 0; rt < 2; ++rt) {
        const bool ok = rt ? ok1 : ok0;
        if (!ok) continue;
        const int rbase = row0 + rt * 16;
        #pragma unroll
        for (int jj = 0; jj < 9; ++jj) {
            const int f = cg * 9 + jj;
            ushort* op; int ldc, colb; const ushort* bp_; bool tobf;
            if (f < 16)      { op = o1; ldc = C1;  colb = f * 16;        bp_ = bi1 + f * 16;        tobf = false; }
            else if (f < 32) { op = o2; ldc = C1;  colb = (f - 16) * 16; bp_ = bi2 + (f - 16) * 16; tobf = false; }
            else             { op = o3; ldc = HID; colb = (f - 32) * 16; bp_ = bi3 + (f - 32) * 16; tobf = true;  }
            const float bb = b2f(bp_[cn]);
            const f32x4 av = rt ? a1[jj] : a0[jj];
            #pragma unroll
            for (int r = 0; r < 4; ++r) {
                const int grow = rbase + cq * 4 + r;
                const float v = av[r] + bb;
                op[(size_t)grow * ldc + colb + cn] = tobf ? f2b(v) : f2h(v);
            }
        }
    }
}

// ---------------- fused layer-2 MFMA GEMM: xl2(64) + xr2(64), K=256 ----------------
__global__ __launch_bounds__(256) void gemm2_k(const ushort* __restrict__ A,
                                               const ushort* __restrict__ B1,
                                               const ushort* __restrict__ B2,
                                               const ushort* __restrict__ bi1,
                                               const ushort* __restrict__ bi2,
                                               ushort* __restrict__ o1,
                                               ushort* __restrict__ o2,
                                               int M) {
    const int wave = threadIdx.x >> 6;
    const int lane = threadIdx.x & 63;
    const int row0 = blockIdx.x * 64 + wave * 16;
    if (row0 >= M) return;
    int arow = row0 + (lane & 15);
    if (arow >= M) arow = M - 1;
    const ushort* aptr = A + (size_t)arow * C1 + (lane >> 4) * 8;
    const bf16x8* b1 = (const bf16x8*)B1;
    const bf16x8* b2 = (const bf16x8*)B2;
    f32x4 aL[4] = {}, aR[4] = {};
    #pragma unroll
    for (int kb = 0; kb < 8; ++kb) {
        bf16x8 af = *(const bf16x8*)(aptr + kb * 32);
        #pragma unroll
        for (int t = 0; t < 4; ++t)
            aL[t] = __builtin_amdgcn_mfma_f32_16x16x32_bf16(af, b1[(kb * 4 + t) * 64 + lane], aL[t], 0, 0, 0);
        #pragma unroll
        for (int t = 0; t < 4; ++t)
            aR[t] = __builtin_amdgcn_mfma_f32_16x16x32_bf16(af, b2[(kb * 4 + t) * 64 + lane], aR[t], 0, 0, 0);
    }
    const int cn = lane & 15, cq = lane >> 4;
    #pragma unroll
    for (int t = 0; t < 4; ++t) {
        float bbL = b2f(bi1[t * 16 + cn]);
        float bbR = b2f(bi2[t * 16 + cn]);
        #pragma unroll
        for (int r = 0; r < 4; ++r) {
            int grow = row0 + cq * 4 + r;
            if (grow < M) {
                // xl2/xr2 stored as fp16 (consumed by packed-f16 conv2)
                o1[(size_t)grow * HID + t * 16 + cn] = f2h(aL[t][r] + bbL);
                o2[(size_t)grow * HID + t * 16 + cn] = f2h(aR[t][r] + bbR);
            }
        }
    }
}

// ---------------- conv1: wave=node, 16-lane group=edge, all 4 heads packed f16 ----------------
// lane = 16*g + r : group g handles edge slots, lane-slot r holds channels 16r..16r+15
// (head of those channels = r>>2; per-head logit reduce = 2 quad-perm DPP adds)
__global__ __launch_bounds__(256) void conv1_k(const ushort* __restrict__ xl,
                                               const ushort* __restrict__ xr,
                                               const int* __restrict__ exc,
                                               const int* __restrict__ cp,
                                               const int* __restrict__ col,
                                               const ushort* __restrict__ att,
                                               const ushort* __restrict__ bias1,
                                               const ushort* __restrict__ g1,
                                               const ushort* __restrict__ b1,
                                               const ushort* __restrict__ m1,
                                               const ushort* __restrict__ v1,
                                               ushort* __restrict__ h1out) {
    const int n = blockIdx.x * 4 + (threadIdx.x >> 6);
    if (n >= N_NODES) return;
    const int lane = threadIdx.x & 63;
    const int g = lane >> 4;                 // edge slot 0..3
    const int r = lane & 15;                 // channel slot: chans 16r..16r+15
    const uint4* xr4 = (const uint4*)(xr + (size_t)n * C1 + r * 16);
    const uint4 xru0 = xr4[0], xru1 = xr4[1];
    const uint4* at4 = (const uint4*)(att + r * 16);
    const uint4 atu0 = at4[0], atu1 = at4[1];
    h2 xrp[8], atp[8];
    xrp[0] = uh(xru0.x); xrp[1] = uh(xru0.y); xrp[2] = uh(xru0.z); xrp[3] = uh(xru0.w);
    xrp[4] = uh(xru1.x); xrp[5] = uh(xru1.y); xrp[6] = uh(xru1.z); xrp[7] = uh(xru1.w);
    atp[0] = uh(atu0.x); atp[1] = uh(atu0.y); atp[2] = uh(atu0.z); atp[3] = uh(atu0.w);
    atp[4] = uh(atu1.x); atp[5] = uh(atu1.y); atp[6] = uh(atu1.z); atp[7] = uh(atu1.w);
    const h2 ns2 = {(_Float16)NEG_SLOPE, (_Float16)NEG_SLOPE};
    const int e0 = exc[n] + cp[n >> 10];
    const int e1 = exc[n + 1] + cp[(n + 1) >> 10];
    float a[16];
    #pragma unroll
    for (int k = 0; k < 16; ++k) a[k] = 0.f;
    float den = 0.f;
    int j = e0 + g;

    auto body = [&](uint4 u0, uint4 u1, bool masked, int jm) {
        h2 xp[8];
        xp[0] = uh(u0.x); xp[1] = uh(u0.y); xp[2] = uh(u0.z); xp[3] = uh(u0.w);
        xp[4] = uh(u1.x); xp[5] = uh(u1.y); xp[6] = uh(u1.z); xp[7] = uh(u1.w);
#if HAS_FDOT2
        float p = 0.f;
        #pragma unroll
        for (int k = 0; k < 8; ++k) {
            h2 t0 = xp[k] + xrp[k];
            t0 = __builtin_elementwise_max(t0, t0 * ns2);
            p = __builtin_amdgcn_fdot2(t0, atp[k], p, false);
        }
#else
        h2 d0 = {(_Float16)0, (_Float16)0};
        h2 d1 = {(_Float16)0, (_Float16)0};
        #pragma unroll
        for (int k = 0; k < 8; k += 2) {
            h2 t0 = xp[k] + xrp[k];
            t0 = __builtin_elementwise_max(t0, t0 * ns2);
            d0 = __builtin_elementwise_fma(t0, atp[k], d0);
            h2 t1 = xp[k + 1] + xrp[k + 1];
            t1 = __builtin_elementwise_max(t1, t1 * ns2);
            d1 = __builtin_elementwise_fma(t1, atp[k + 1], d1);
        }
        h2 ds = d0 + d1;
        float p = (float)ds.x + (float)ds.y;
#endif
        p = dpp_add<0xB1>(p);    // quad xor1
        p = dpp_add<0x4E>(p);    // quad xor2 -> per-head logit
        float w = __expf(fminf(p, 60.f));
        if (masked) w = (jm < e1) ? w : 0.f;
        den += w;
        #pragma unroll
        for (int k = 0; k < 8; ++k) {
            a[2 * k]     = fmaf(w, (float)xp[k].x, a[2 * k]);
            a[2 * k + 1] = fmaf(w, (float)xp[k].y, a[2 * k + 1]);
        }
    };
    auto rowp = [&](int s) { return (const uint4*)(xl + (size_t)(uint)s * C1 + r * 16); };

    int sA = col[j < e1 ? j : e1 - 1];
    int sB = col[j + 4 < e1 ? j + 4 : e1 - 1];
    int i = e0;
    for (; i + 8 <= e1; i += 8) {
        const int jn = i + g + 8;
        int sC = col[jn < e1 ? jn : e1 - 1];
        int sD = col[jn + 4 < e1 ? jn + 4 : e1 - 1];
        const uint4* pA = rowp(sA);
        uint4 a0 = pA[0], a1 = pA[1];
        const uint4* pB = rowp(sB);
        uint4 b0 = pB[0], b1v = pB[1];
        body(a0, a1, false, 0);
        body(b0, b1v, false, 0);
        sA = sC; sB = sD;
    }
    j = i + g;
    if (i + 4 <= e1) {                       // one more full 4-edge round
        const uint4* pA = rowp(sA);
        uint4 a0 = pA[0], a1 = pA[1];
        body(a0, a1, false, 0);
        sA = sB; i += 4; j += 4;
    }
    if (j < e1) {                            // masked tail (0..3 edges)
        const uint4* pA = rowp(sA);
        uint4 a0 = pA[0], a1 = pA[1];
        body(a0, a1, true, j);
    }

    // reduce across the 4 edge-groups
    #pragma unroll
    for (int k = 0; k < 16; ++k) {
        a[k] += __shfl_xor(a[k], 16);
        a[k] += __shfl_xor(a[k], 32);
    }
    den += __shfl_xor(den, 16);
    den += __shfl_xor(den, 32);
    // lane (16q+r) finalizes channels 16r+4q..+3  (static select, no scratch)
    const int q = g;
    float s0 = q == 0 ? a[0] : q == 1 ? a[4] : q == 2 ? a[8]  : a[12];
    float s1 = q == 0 ? a[1] : q == 1 ? a[5] : q == 2 ? a[9]  : a[13];
    float s2 = q == 0 ? a[2] : q == 1 ? a[6] : q == 2 ? a[10] : a[14];
    float s3 = q == 0 ? a[3] : q == 1 ? a[7] : q == 2 ? a[11] : a[15];
    const int pi = r * 4 + q;                // uint2 index of 4-channel chunk
    const float inv = 1.f / den;
    const uint2 biu = ((const uint2*)bias1)[pi];
    const uint2 gu  = ((const uint2*)g1)[pi];
    const uint2 bu  = ((const uint2*)b1)[pi];
    const uint2 mu  = ((const uint2*)m1)[pi];
    const uint2 vu  = ((const uint2*)v1)[pi];
    float o0 = fmaf(s0, inv, lo16(biu.x));
    float o1 = fmaf(s1, inv, hi16(biu.x));
    float o2 = fmaf(s2, inv, lo16(biu.y));
    float o3 = fmaf(s3, inv, hi16(biu.y));
    float c0 = lo16(gu.x) * rsqrtf(lo16(vu.x) + BN_EPS);
    float c1 = hi16(gu.x) * rsqrtf(hi16(vu.x) + BN_EPS);
    float c2 = lo16(gu.y) * rsqrtf(lo16(vu.y) + BN_EPS);
    float c3 = hi16(gu.y) * rsqrtf(hi16(vu.y) + BN_EPS);
    float h0 = fmaxf((o0 - lo16(mu.x)) * c0 + lo16(bu.x), 0.f);
    float h1v = fmaxf((o1 - hi16(mu.x)) * c1 + hi16(bu.x), 0.f);
    float h2v = fmaxf((o2 - lo16(mu.y)) * c2 + lo16(bu.y), 0.f);
    float h3 = fmaxf((o3 - hi16(mu.y)) * c3 + hi16(bu.y), 0.f);
    uint2 ou;
    ou.x = (uint)f2b(h0) | ((uint)f2b(h1v) << 16);
    ou.y = (uint)f2b(h2v) | ((uint)f2b(h3) << 16);
    ((uint2*)h1out)[(size_t)n * 64 + pi] = ou;   // h1 stays bf16 (gemm2 MFMA input)
}

// ---------------- conv2 + BN2 + relu + skip + output linear (packed f16 edges) ----------------
__global__ __launch_bounds__(256) void conv2_k(const ushort* __restrict__ xl,
                                               const ushort* __restrict__ xr,
                                               const ushort* __restrict__ xskip,
                                               const int* __restrict__ exc,
                                               const int* __restrict__ cp,
                                               const int* __restrict__ col,
                                               const ushort* __restrict__ att2,
                                               const ushort* __restrict__ bias2,
                                               const ushort* __restrict__ g2,
                                               const ushort* __restrict__ bb2,
                                               const ushort* __restrict__ m2,
                                               const ushort* __restrict__ v2,
                                               const ushort* __restrict__ Wo,
                                               const ushort* __restrict__ bo,
                                               void* __restrict__ out,
                                               const ushort* __restrict__ xraw) {
    const bool f32out = probe_f32(xraw);
    const int n = blockIdx.x * 4 + (threadIdx.x >> 6);
    if (n >= N_NODES) return;
    const int lane = threadIdx.x & 63;
    const int grp = lane >> 4;
    const uint m = lane & 15;                // uint2 index within 16-uint2 row
    const uint2* xl2v = (const uint2*)xl;
    const uint2 xru = ((const uint2*)xr)[(size_t)n * 16 + m];   // f16
    const h2 xr01 = uh(xru.x), xr23 = uh(xru.y);
    const uint2 atu = ((const uint2*)att2)[m];                  // f16
    const h2 at01 = uh(atu.x), at23 = uh(atu.y);
    const h2 ns2 = {(_Float16)NEG_SLOPE, (_Float16)NEG_SLOPE};
    const int e0 = exc[n] + cp[n >> 10];
    const int e1 = exc[n + 1] + cp[(n + 1) >> 10];
    const int deg = e1 - e0;
    const int iend = e0 + (deg & ~15);
    float a0 = 0.f, a1 = 0.f, a2 = 0.f, a3 = 0.f, den = 0.f;

    auto edge4 = [&](const uint2 xu, bool masked, int jbase) {
        const h2 x01 = uh(xu.x), x23 = uh(xu.y);
        h2 t01 = x01 + xr01;
        t01 = __builtin_elementwise_max(t01, t01 * ns2);
        h2 t23 = x23 + xr23;
        t23 = __builtin_elementwise_max(t23, t23 * ns2);
#if HAS_FDOT2
        float p = __builtin_amdgcn_fdot2(t01, at01, 0.f, false);
        p = __builtin_amdgcn_fdot2(t23, at23, p, false);
#else
        h2 dp = __builtin_elementwise_fma(t23, at23, t01 * at01);
        float p = (float)dp.x + (float)dp.y;
#endif
        p = row16_sum(p);
        float w;
        if (masked) {
            w = __expf(fminf(p, 60.f));
            w = ((jbase + grp) < e1) ? w : 0.f;
        } else {
            w = __expf(p);   // logits bounded; no clamp in hot path
        }
        a0 = fmaf(w, (float)x01.x, a0);
        a1 = fmaf(w, (float)x01.y, a1);
        a2 = fmaf(w, (float)x23.x, a2);
        a3 = fmaf(w, (float)x23.y, a3);
        den += w;
    };

    uint s0_, s1_, s2_, s3_;
    {
        const int j0 = e0 + grp, j1 = j0 + 4, j2 = j0 + 8, j3 = j0 + 12;
        s0_ = (uint)col[j0 < e1 ? j0 : e1 - 1];
        s1_ = (uint)col[j1 < e1 ? j1 : e1 - 1];
        s2_ = (uint)col[j2 < e1 ? j2 : e1 - 1];
        s3_ = (uint)col[j3 < e1 ? j3 : e1 - 1];
    }
    for (int i = e0; i < iend; i += 16) {
        const uint2 xu0 = xl2v[(s0_ << 4) + m];
        const uint2 xu1 = xl2v[(s1_ << 4) + m];
        const uint2 xu2 = xl2v[(s2_ << 4) + m];
        const uint2 xu3 = xl2v[(s3_ << 4) + m];
        const int j0 = i + 16 + grp, j1 = j0 + 4, j2 = j0 + 8, j3 = j0 + 12;
        s0_ = (uint)col[j0 < e1 ? j0 : e1 - 1];
        s1_ = (uint)col[j1 < e1 ? j1 : e1 - 1];
        s2_ = (uint)col[j2 < e1 ? j2 : e1 - 1];
        s3_ = (uint)col[j3 < e1 ? j3 : e1 - 1];
        edge4(xu0, false, 0);
        edge4(xu1, false, 0);
        edge4(xu2, false, 0);
        edge4(xu3, false, 0);
    }
    const int rem = e1 - iend;
    if (rem > 0) {
        const uint2 xu0 = xl2v[(s0_ << 4) + m];
        const uint2 xu1 = xl2v[(s1_ << 4) + m];
        const uint2 xu2 = xl2v[(s2_ << 4) + m];
        const uint2 xu3 = xl2v[(s3_ << 4) + m];
        edge4(xu0, true, iend);
        if (rem > 4)  edge4(xu1, true, iend + 4);
        if (rem > 8)  edge4(xu2, true, iend + 8);
        if (rem > 12) edge4(xu3, true, iend + 12);
    }
    a0 += __shfl_xor(a0, 16); a0 += __shfl_xor(a0, 32);
    a1 += __shfl_xor(a1, 16); a1 += __shfl_xor(a1, 32);
    a2 += __shfl_xor(a2, 16); a2 += __shfl_xor(a2, 32);
    a3 += __shfl_xor(a3, 16); a3 += __shfl_xor(a3, 32);
    den += __shfl_xor(den, 16); den += __shfl_xor(den, 32);
    if (lane < 16) {
        const float inv = 1.f / den;
        const uint2 biu = ((const uint2*)bias2)[m];
        const uint2 gu  = ((const uint2*)g2)[m];
        const uint2 bu  = ((const uint2*)bb2)[m];
        const uint2 mu  = ((const uint2*)m2)[m];
        const uint2 vu  = ((const uint2*)v2)[m];
        const uint2 sku = ((const uint2*)xskip)[(size_t)n * 16 + m];
        const uint2 wou = ((const uint2*)Wo)[m];
        float o0 = fmaf(a0, inv, lo16(biu.x));
        float o1 = fmaf(a1, inv, hi16(biu.x));
        float o2 = fmaf(a2, inv, lo16(biu.y));
        float o3 = fmaf(a3, inv, hi16(biu.y));
        float s0 = lo16(gu.x) * rsqrtf(lo16(vu.x) + BN_EPS);
        float s1 = hi16(gu.x) * rsqrtf(hi16(vu.x) + BN_EPS);
        float s2 = lo16(gu.y) * rsqrtf(lo16(vu.y) + BN_EPS);
        float s3 = hi16(gu.y) * rsqrtf(hi16(vu.y) + BN_EPS);
        float h0 = fmaxf((o0 - lo16(mu.x)) * s0 + lo16(bu.x), 0.f) + lo16(sku.x);
        float h1v = fmaxf((o1 - hi16(mu.x)) * s1 + hi16(bu.x), 0.f) + hi16(sku.x);
        float h2v = fmaxf((o2 - lo16(mu.y)) * s2 + lo16(bu.y), 0.f) + lo16(sku.y);
        float h3 = fmaxf((o3 - hi16(mu.y)) * s3 + hi16(bu.y), 0.f) + hi16(sku.y);
        float d = fmaf(h0, lo16(wou.x), fmaf(h1v, hi16(wou.x),
                  fmaf(h2v, lo16(wou.y), h3 * hi16(wou.y))));
        d = row16_sum(d);
        if (m == 0) {
            float r = d + b2f(bo[0]);
            if (f32out) ((float*)out)[n] = r;
            else        ((ushort*)out)[n] = f2b(r);
        }
    }
}

extern "C" void kernel_launch(void* const* d_in, const int* in_sizes, int n_in,
                              void* d_out, int out_size, void* d_ws, size_t ws_size,
                              hipStream_t stream) {
    char* ws = (char*)d_ws;
    size_t off = 0;
    auto alloc = [&](size_t bytes) -> void* {
        void* p = ws + off;
        off += (bytes + 255) & ~(size_t)255;
        return p;
    };
    ushort* params  = (ushort*)alloc((size_t)127617 * 2);
    int*    exc     = (int*)alloc((size_t)(N_NODES + 1) * 4);
    int*    deg     = (int*)alloc((size_t)N_NODES * 4);
    int*    epos    = (int*)alloc((size_t)EP_EDGES * 4);
    int*    colbuf  = (int*)alloc((size_t)EP_EDGES * 4);
    int*    bsum    = (int*)alloc(64 * 4);
    int*    cparr   = (int*)alloc(64 * 4);
    ushort* xl1     = (ushort*)alloc((size_t)N_NODES * C1 * 2);
    ushort* xr1     = (ushort*)alloc((size_t)N_NODES * C1 * 2);
    ushort* xskip   = (ushort*)alloc((size_t)N_NODES * HID * 2);
    ushort* h1      = (ushort*)alloc((size_t)N_NODES * C1 * 2);
    ushort* xl2     = (ushort*)alloc((size_t)N_NODES * HID * 2);
    ushort* xr2     = (ushort*)alloc((size_t)N_NODES * HID * 2);
    ushort* swzU    = (ushort*)alloc((size_t)5 * 36 * 64 * 8 * 2);   // unified Wl1|Wr1|Ws frags
    ushort* swzWl2  = (ushort*)alloc((size_t)C1 * HID * 2);
    ushort* swzWr2  = (ushort*)alloc((size_t)C1 * HID * 2);
    ushort* Abf     = (ushort*)alloc((size_t)N_NODES * IN_DIM * 2);  // x as contiguous bf16

    ushort* bl1c   = params + 40960;
    ushort* br1c   = params + 82176;
    ushort* att1c  = params + 82432;
    ushort* bias1c = params + 82688;
    ushort* g1c    = params + 82944;
    ushort* b1c    = params + 83200;
    ushort* m1c    = params + 83456;
    ushort* v1c    = params + 83712;
    ushort* bl2c   = params + 100352;
    ushort* br2c   = params + 116800;
    ushort* att2c  = params + 116864;
    ushort* bias2c = params + 116928;
    ushort* g2c    = params + 116992;
    ushort* b2c    = params + 117056;
    ushort* m2c    = params + 117120;
    ushort* v2c    = params + 117184;
    ushort* bsc    = params + 127488;
    ushort* Woc    = params + 127552;
    ushort* boc    = params + 127616;

    const int* ei_raw = (const int*)d_in[1];

    // ---- deg = 0 (needed by fused hist) ----
    (void)hipMemsetAsync(deg, 0, (size_t)N_NODES * 4, stream);

    // ---- fused front-end: swizzle+params | A->bf16 | hist(+epos) ----
    SW2 sw;
    sw.W[0] = d_in[2];  sw.D[0] = nullptr; sw.NT[0] = 16; sw.base[0] = 0;      // Wl1 -> U
    sw.W[1] = d_in[4];  sw.D[1] = nullptr; sw.NT[1] = 16; sw.base[1] = 5120;   // Wr1 -> U
    sw.W[2] = d_in[22]; sw.D[2] = nullptr; sw.NT[2] = 4;  sw.base[2] = 10240;  // Ws  -> U
    sw.W[3] = d_in[12]; sw.D[3] = swzWl2;  sw.NT[3] = 4;  sw.base[3] = 11520;  // Wl2
    sw.W[4] = d_in[14]; sw.D[4] = swzWr2;  sw.NT[4] = 4;  sw.base[4] = 13568;  // Wr2
    sw.U = swzU;
    const int spidx[19] = {3,5,6,7,8,9,10,11, 13,15,16,17,18,19,20,21, 23,24, 25};
    for (int i = 0; i < 19; ++i) sw.sp[i] = d_in[spidx[i]];
    sw.xraw = d_in[0];
    front_k<<<NB_SWZ + NB_CVT + NB_HIST, 256, 0, stream>>>(ei_raw, deg, epos, sw, params, Abf);

    const int NB_S = (N_NODES + 1023) / 1024;      // 49

    // ---- CSR scan (2 launches) ----
    scan1_k<<<NB_S, 1024, 0, stream>>>(deg, exc, bsum);
    scan2_k<<<1, 64, 0, stream>>>(bsum, cparr, exc);

    // ---- fused: gemm3 | scatter (overlapped in one launch) ----
    gemm3_k<<<NB_G3F + NB_HIST, 256, 0, stream>>>(Abf, swzU, bl1c, br1c, bsc,
                                                  xl1, xr1, xskip, N_NODES,
                                                  ei_raw, epos, exc, cparr, colbuf);

    // ---- conv1 edge aggregation + BN1 + relu (wave=node, 4 heads packed) ----
    conv1_k<<<(N_NODES + 3) / 4, 256, 0, stream>>>(xl1, xr1, exc, cparr, colbuf,
                                                   att1c, bias1c, g1c, b1c, m1c, v1c, h1);

    // ---- layer-2 linear transforms, fused MFMA ----
    gemm2_k<<<(N_NODES + 63) / 64, 256, 0, stream>>>(h1, swzWl2, swzWr2, bl2c, br2c,
                                                     xl2, xr2, N_NODES);

    // ---- conv2 + BN2 + relu + skip + output linear ----
    conv2_k<<<(N_NODES + 3) / 4, 256, 0, stream>>>(xl2, xr2, xskip, exc, cparr, colbuf,
                                                   att2c, bias2c, g2c, b2c, m2c, v2c,
                                                   Woc, boc, d_out, (const ushort*)d_in[0]);
}